// Round 1
// baseline (1683.435 us; speedup 1.0000x reference)
//
#include <hip/hip_runtime.h>
#include <math.h>

namespace {

constexpr int kT = 128, kB = 512, kD = 512, kM = 6, kH = 2;
constexpr int kJ = kT + kM;          // 134
constexpr float kBG = 0.1f;
constexpr int kTB = kT * kB;         // 65536 rows
constexpr int kBK = 32;              // K-tile for MFMA kernels

typedef __attribute__((ext_vector_type(8))) short bf16x8;
typedef __attribute__((ext_vector_type(4))) float f32x4;
typedef __attribute__((ext_vector_type(8))) unsigned short us8;
typedef __attribute__((ext_vector_type(4))) unsigned short us4;

__device__ __forceinline__ float sigmoidf_(float x) {
  return 1.0f / (1.0f + __expf(-x));
}

__device__ __forceinline__ unsigned short bf16u(float f) {
  union { float f; unsigned u; } c; c.f = f;
  unsigned r = c.u + 0x7fffu + ((c.u >> 16) & 1u);
  return (unsigned short)(r >> 16);
}

__device__ __forceinline__ float b2f(unsigned short u) {
  union { unsigned u; float f; } c; c.u = (unsigned)u << 16;
  return c.f;
}

__device__ __forceinline__ void gl_lds16(const void* g, void* l) {
  __builtin_amdgcn_global_load_lds(
      (const __attribute__((address_space(1))) unsigned int*)g,
      (__attribute__((address_space(3))) unsigned int*)l, 16, 0, 0);
}

// ---- transpose + cast: W fp32 [K][N] -> Wt bf16 [N][K]; dims mult of 32 ----
__global__ __launch_bounds__(256) void transp_kernel(const float* __restrict__ W,
                                                     unsigned short* __restrict__ Wt,
                                                     int K, int N) {
  __shared__ float t[32][33];
  const int n0 = blockIdx.x * 32, k0 = blockIdx.y * 32;
  const float* Wb = W + (size_t)blockIdx.z * K * N;
  unsigned short* Wtb = Wt + (size_t)blockIdx.z * K * N;
  int tx = threadIdx.x & 31, ty = threadIdx.x >> 5;  // 32 x 8
#pragma unroll
  for (int r = 0; r < 32; r += 8)
    t[ty + r][tx] = Wb[(size_t)(k0 + ty + r) * N + n0 + tx];
  __syncthreads();
#pragma unroll
  for (int r = 0; r < 32; r += 8)
    Wtb[(size_t)(n0 + ty + r) * K + k0 + tx] = bf16u(t[tx][ty + r]);
}

// ---- fp32 -> bf16 elementwise (n multiple of 8) ----
__global__ __launch_bounds__(256) void conv_bf16_kernel(const float* __restrict__ in,
                                                        unsigned short* __restrict__ outb,
                                                        size_t n) {
  size_t idx = ((size_t)blockIdx.x * 256 + threadIdx.x) * 8;
  if (idx >= n) return;
  float4 a = *(const float4*)(in + idx);
  float4 c = *(const float4*)(in + idx + 4);
  us8 o;
  o[0] = bf16u(a.x); o[1] = bf16u(a.y); o[2] = bf16u(a.z); o[3] = bf16u(a.w);
  o[4] = bf16u(c.x); o[5] = bf16u(c.y); o[6] = bf16u(c.z); o[7] = bf16u(c.w);
  *(us8*)(outb + idx) = o;
}

// ---- LN1 dual-output: LN(x) -> bf16 AND raw x -> bf16, one fp32 read ----
__global__ __launch_bounds__(256) void ln1_dual_kernel(const float* __restrict__ in,
                                                       const float* __restrict__ g,
                                                       const float* __restrict__ b,
                                                       unsigned short* __restrict__ outLN,
                                                       unsigned short* __restrict__ outRaw,
                                                       int nrows) {
  int wave = threadIdx.x >> 6, lane = threadIdx.x & 63;
  int row = blockIdx.x * 4 + wave;
  if (row >= nrows) return;
  const float* p = in + (size_t)row * kD + lane * 8;
  float4 a = *(const float4*)p;
  float4 c = *(const float4*)(p + 4);
  float v[8] = {a.x, a.y, a.z, a.w, c.x, c.y, c.z, c.w};
  float s = 0.f;
#pragma unroll
  for (int i = 0; i < 8; ++i) s += v[i];
#pragma unroll
  for (int off = 32; off; off >>= 1) s += __shfl_xor(s, off);
  float mu = s * (1.0f / 512.0f);
  float q = 0.f;
#pragma unroll
  for (int i = 0; i < 8; ++i) { float d = v[i] - mu; q += d * d; }
#pragma unroll
  for (int off = 32; off; off >>= 1) q += __shfl_xor(q, off);
  float rstd = rsqrtf(q * (1.0f / 512.0f) + 1e-5f);
  us8 oln, oraw;
#pragma unroll
  for (int i = 0; i < 8; ++i) {
    int col = lane * 8 + i;
    oln[i] = bf16u((v[i] - mu) * rstd * g[col] + b[col]);
    oraw[i] = bf16u(v[i]);
  }
  size_t off8 = (size_t)row * kD + lane * 8;
  *(us8*)(outLN + off8) = oln;
  *(us8*)(outRaw + off8) = oraw;
}

// ---- LN with bf16 input -> bf16 out ----
__global__ __launch_bounds__(256) void ln_b16_kernel(const unsigned short* __restrict__ in,
                                                     const float* __restrict__ g,
                                                     const float* __restrict__ b,
                                                     unsigned short* __restrict__ outb,
                                                     int nrows) {
  int wave = threadIdx.x >> 6, lane = threadIdx.x & 63;
  int row = blockIdx.x * 4 + wave;
  if (row >= nrows) return;
  us8 iv = *(const us8*)(in + (size_t)row * kD + lane * 8);
  float v[8];
#pragma unroll
  for (int i = 0; i < 8; ++i) v[i] = b2f(iv[i]);
  float s = 0.f;
#pragma unroll
  for (int i = 0; i < 8; ++i) s += v[i];
#pragma unroll
  for (int off = 32; off; off >>= 1) s += __shfl_xor(s, off);
  float mu = s * (1.0f / 512.0f);
  float q = 0.f;
#pragma unroll
  for (int i = 0; i < 8; ++i) { float d = v[i] - mu; q += d * d; }
#pragma unroll
  for (int off = 32; off; off >>= 1) q += __shfl_xor(q, off);
  float rstd = rsqrtf(q * (1.0f / 512.0f) + 1e-5f);
  us8 o;
#pragma unroll
  for (int i = 0; i < 8; ++i) {
    int col = lane * 8 + i;
    o[i] = bf16u((v[i] - mu) * rstd * g[col] + b[col]);
  }
  *(us8*)(outb + (size_t)row * kD + lane * 8) = o;
}

// ============ MFMA GEMM, B^T input: C[M][N] = A[M][K] @ Bt[N][K]^T ==========
// 128 x TN tile, 256 threads (4 waves), BK=32, global_load_lds width 16.
// EPI: 0 = fp32 out, 1 = bf16 out, 2 = bias+relu+bf16, 3 = bias+bf16.
template <int TN, int EPI>
__global__ __launch_bounds__(256) void mfma_gemm_bt(
    const unsigned short* __restrict__ A, const unsigned short* __restrict__ Bt,
    int K, const float* __restrict__ bias, void* __restrict__ Cv, int N) {
  constexpr int MI = (TN == 128) ? 4 : 2;
  constexpr int NJ = 4;
  constexpr int BCH = TN * 64 / 1024;
  __shared__ __align__(16) unsigned short As[128 * kBK];
  __shared__ __align__(16) unsigned short Bs[TN * kBK];
  const int tid = threadIdx.x;
  const int lane = tid & 63, wv = tid >> 6;
  const int ml = lane & 15, qd = lane >> 4;
  const int m0 = blockIdx.y * 128, n0 = blockIdx.x * TN;
  const int mw0 = (TN == 128) ? (wv >> 1) * 64 : wv * 32;
  const int nw0 = (TN == 128) ? (wv & 1) * 64 : 0;
  const size_t ldA = (size_t)K * 2, ldB = (size_t)K * 2;
  const char* Ab = (const char*)A + (size_t)m0 * ldA;
  const char* Bb = (const char*)Bt + (size_t)n0 * ldB;
  f32x4 acc[MI][NJ];
#pragma unroll
  for (int i = 0; i < MI; ++i)
#pragma unroll
    for (int j = 0; j < NJ; ++j) acc[i][j] = (f32x4)0.f;
  for (int k0 = 0; k0 < K; k0 += kBK) {
#pragma unroll
    for (int c = wv; c < 8; c += 4) {
      int fb = c * 1024 + lane * 16;
      gl_lds16(Ab + (size_t)(fb >> 6) * ldA + (fb & 63) + (size_t)k0 * 2,
               (char*)As + c * 1024);
    }
#pragma unroll
    for (int c = wv; c < BCH; c += 4) {
      int fb = c * 1024 + lane * 16;
      gl_lds16(Bb + (size_t)(fb >> 6) * ldB + (fb & 63) + (size_t)k0 * 2,
               (char*)Bs + c * 1024);
    }
    __syncthreads();
    bf16x8 af[MI], bfr[NJ];
#pragma unroll
    for (int i = 0; i < MI; ++i)
      af[i] = *(const bf16x8*)(As + (mw0 + i * 16 + ml) * kBK + qd * 8);
#pragma unroll
    for (int j = 0; j < NJ; ++j)
      bfr[j] = *(const bf16x8*)(Bs + (nw0 + j * 16 + ml) * kBK + qd * 8);
#pragma unroll
    for (int i = 0; i < MI; ++i)
#pragma unroll
      for (int j = 0; j < NJ; ++j)
        acc[i][j] = __builtin_amdgcn_mfma_f32_16x16x32_bf16(af[i], bfr[j], acc[i][j], 0, 0, 0);
    __syncthreads();
  }
#pragma unroll
  for (int i = 0; i < MI; ++i)
#pragma unroll
    for (int j = 0; j < NJ; ++j)
#pragma unroll
      for (int r = 0; r < 4; ++r) {
        int m = m0 + mw0 + i * 16 + qd * 4 + r;
        int n = n0 + nw0 + j * 16 + ml;
        float val = acc[i][j][r];
        if (EPI >= 2) val += bias[n];
        if (EPI == 2) val = fmaxf(val, 0.f);
        size_t idx = (size_t)m * N + n;
        if (EPI == 0) ((float*)Cv)[idx] = val;
        else ((unsigned short*)Cv)[idx] = bf16u(val);
      }
}

// XCD swizzle: 1-D grid of MG*NB blocks. All NB n-blocks of one m-group land
// on the SAME XCD in ADJACENT dispatch slots -> A tile fetched once into that
// XCD's L2 and shared (perf-only heuristic; correctness never depends on it).
template <int NBLOG>
__device__ __forceinline__ void xcd_decode(int& m0, int& n0, int tileN) {
  const int L = blockIdx.x;
  const int xcd = L & 7;
  const int s = L >> 3;
  const int mgPerX = (int)(gridDim.x >> (3 + NBLOG));
  const int mg = xcd * mgPerX + (s >> NBLOG);
  const int nb = s & ((1 << NBLOG) - 1);
  m0 = mg * 128;
  n0 = nb * tileN;
}

// ====== gate stage A: acc = [Y|X] (K=1024) @ [[W0,W2],[W1,W3]] (N=1024).
// 128x256 tile, 512 threads (8 waves, 2M x 4N), per-wave 64x64, 4x4 acc
// (16 MFMA/wave per barrier-pair = the proven m97 ratio).
// n-tile < 512:  RX = bf16(sigmoid(acc + b0 + b1) * X)
// n-tile >= 512: Zp = acc (fp32, raw pre-activation; bias applied in stage B)
__global__ __launch_bounds__(512, 4) void mfma_gate_a(
    const unsigned short* __restrict__ Yb, const unsigned short* __restrict__ Xb,
    const unsigned short* __restrict__ Wt, const float* __restrict__ gb,
    unsigned short* __restrict__ RX, float* __restrict__ Zp) {
  __shared__ __align__(16) unsigned short As[128 * kBK];   // 8 KB
  __shared__ __align__(16) unsigned short Bs[256 * kBK];   // 16 KB
  const int tid = threadIdx.x;
  const int lane = tid & 63, wv = tid >> 6;  // 8 waves
  const int ml = lane & 15, qd = lane >> 4;
  int m0, n0;
  xcd_decode<2>(m0, n0, 256);                // grid = MG*4
  const int nhalf = n0 >> 9;                 // 0 = r-path, 1 = z-path
  const int n0e = n0 & 511;                  // 0 or 256
  const int mw0 = (wv & 1) * 64, nw0 = (wv >> 1) * 64;
  const size_t ld = (size_t)kD * 2;
  const size_t DD = (size_t)kD * kD;
  f32x4 acc[4][4];
#pragma unroll
  for (int i = 0; i < 4; ++i)
#pragma unroll
    for (int j = 0; j < 4; ++j) acc[i][j] = (f32x4)0.f;
  for (int p = 0; p < 2; ++p) {
    const char* Ab = (const char*)(p ? Xb : Yb) + (size_t)m0 * ld;
    const char* Bb = (const char*)(Wt + (size_t)(2 * nhalf + p) * DD) + (size_t)n0e * ld;
    for (int k0 = 0; k0 < kD; k0 += kBK) {
      {  // A: 8 chunks / 8 waves
        int fb = wv * 1024 + lane * 16;
        gl_lds16(Ab + (size_t)(fb >> 6) * ld + (fb & 63) + (size_t)k0 * 2,
                 (char*)As + wv * 1024);
      }
#pragma unroll
      for (int c = wv; c < 16; c += 8) {  // B: 16 chunks / 8 waves
        int fb = c * 1024 + lane * 16;
        gl_lds16(Bb + (size_t)(fb >> 6) * ld + (fb & 63) + (size_t)k0 * 2,
                 (char*)Bs + c * 1024);
      }
      __syncthreads();
      bf16x8 af[4], bfr[4];
#pragma unroll
      for (int i = 0; i < 4; ++i)
        af[i] = *(const bf16x8*)(As + (mw0 + i * 16 + ml) * kBK + qd * 8);
#pragma unroll
      for (int j = 0; j < 4; ++j)
        bfr[j] = *(const bf16x8*)(Bs + (nw0 + j * 16 + ml) * kBK + qd * 8);
#pragma unroll
      for (int i = 0; i < 4; ++i)
#pragma unroll
        for (int j = 0; j < 4; ++j)
          acc[i][j] = __builtin_amdgcn_mfma_f32_16x16x32_bf16(af[i], bfr[j], acc[i][j], 0, 0, 0);
      __syncthreads();
    }
  }
  if (nhalf == 0) {
#pragma unroll
    for (int i = 0; i < 4; ++i)
#pragma unroll
      for (int j = 0; j < 4; ++j)
#pragma unroll
        for (int r = 0; r < 4; ++r) {
          int m = m0 + mw0 + i * 16 + qd * 4 + r;
          int n = n0e + nw0 + j * 16 + ml;
          float rg = sigmoidf_(acc[i][j][r] + gb[n] + gb[kD + n]);
          size_t idx = (size_t)m * kD + n;
          RX[idx] = bf16u(rg * b2f(Xb[idx]));
        }
  } else {
#pragma unroll
    for (int i = 0; i < 4; ++i)
#pragma unroll
      for (int j = 0; j < 4; ++j)
#pragma unroll
        for (int r = 0; r < 4; ++r) {
          int m = m0 + mw0 + i * 16 + qd * 4 + r;
          int n = n0e + nw0 + j * 16 + ml;
          Zp[(size_t)m * kD + n] = acc[i][j][r];
        }
  }
}

// ====== gate stage B: acc = [Y|RX] (K=1024) @ [[W4],[W5]] (N=512).
// 128x256 tile, 8 waves, per-wave 64x64, 4x4 acc. Epilogue:
// z = sigmoid(Zp + b2 + b3 - BG), h = tanh(acc + b4 + b5),
// out = (1-z)*x + z*h. POOL=false: bf16 -> OUTb. POOL=true: fp32 in-place
// over Zp (no atomics; a separate pool kernel reduces over t afterwards).
template <bool POOL>
__global__ __launch_bounds__(512, 4) void mfma_gate_b(
    const unsigned short* __restrict__ Yb, const unsigned short* __restrict__ RXb,
    const unsigned short* __restrict__ Xb, const unsigned short* __restrict__ Wt,
    const float* __restrict__ gb, float* Zp, unsigned short* __restrict__ OUTb) {
  __shared__ __align__(16) unsigned short As[128 * kBK];   // 8 KB
  __shared__ __align__(16) unsigned short Bs[256 * kBK];   // 16 KB
  const int tid = threadIdx.x;
  const int lane = tid & 63, wv = tid >> 6;  // 8 waves
  const int ml = lane & 15, qd = lane >> 4;
  int m0, n0;
  xcd_decode<1>(m0, n0, 256);                // grid = MG*2
  const int mw0 = (wv & 1) * 64, nw0 = (wv >> 1) * 64;
  const size_t ld = (size_t)kD * 2;
  const size_t DD = (size_t)kD * kD;
  f32x4 acc[4][4];
#pragma unroll
  for (int i = 0; i < 4; ++i)
#pragma unroll
    for (int j = 0; j < 4; ++j) acc[i][j] = (f32x4)0.f;
  for (int p = 0; p < 2; ++p) {
    const char* Ab = (const char*)(p ? RXb : Yb) + (size_t)m0 * ld;
    const char* Bb = (const char*)(Wt + (size_t)(4 + p) * DD) + (size_t)n0 * ld;
    for (int k0 = 0; k0 < kD; k0 += kBK) {
      {  // A: 8 chunks / 8 waves
        int fb = wv * 1024 + lane * 16;
        gl_lds16(Ab + (size_t)(fb >> 6) * ld + (fb & 63) + (size_t)k0 * 2,
                 (char*)As + wv * 1024);
      }
#pragma unroll
      for (int c = wv; c < 16; c += 8) {  // B: 16 chunks / 8 waves
        int fb = c * 1024 + lane * 16;
        gl_lds16(Bb + (size_t)(fb >> 6) * ld + (fb & 63) + (size_t)k0 * 2,
                 (char*)Bs + c * 1024);
      }
      __syncthreads();
      bf16x8 af[4], bfr[4];
#pragma unroll
      for (int i = 0; i < 4; ++i)
        af[i] = *(const bf16x8*)(As + (mw0 + i * 16 + ml) * kBK + qd * 8);
#pragma unroll
      for (int j = 0; j < 4; ++j)
        bfr[j] = *(const bf16x8*)(Bs + (nw0 + j * 16 + ml) * kBK + qd * 8);
#pragma unroll
      for (int i = 0; i < 4; ++i)
#pragma unroll
        for (int j = 0; j < 4; ++j)
          acc[i][j] = __builtin_amdgcn_mfma_f32_16x16x32_bf16(af[i], bfr[j], acc[i][j], 0, 0, 0);
      __syncthreads();
    }
  }
#pragma unroll
  for (int i = 0; i < 4; ++i)
#pragma unroll
    for (int j = 0; j < 4; ++j)
#pragma unroll
      for (int r = 0; r < 4; ++r) {
        int m = m0 + mw0 + i * 16 + qd * 4 + r;
        int n = n0 + nw0 + j * 16 + ml;
        size_t idx = (size_t)m * kD + n;
        float z = sigmoidf_(Zp[idx] + gb[2 * kD + n] + gb[3 * kD + n] - kBG);
        float hc = tanhf(acc[i][j][r] + gb[4 * kD + n] + gb[5 * kD + n]);
        float val = (1.0f - z) * b2f(Xb[idx]) + z * hc;
        if (POOL) Zp[idx] = val;            // same thread read idx above: safe
        else OUTb[idx] = bf16u(val);
      }
}

// ---- chunk mean-pool: TS[b][n] += (1/T) * sum_t OUT[t*512+b][n] (fp32 in).
// One block per b; 4 waves split t; LDS combine. No atomics (chunks serial).
__global__ __launch_bounds__(256) void pool_kernel(const float* __restrict__ OUT,
                                                   float* __restrict__ TS, int Tc) {
  __shared__ float sh[4][512];
  const int b = blockIdx.x;
  const int w = threadIdx.x >> 6, l = threadIdx.x & 63;
  float acc[8] = {};
  for (int t = w; t < Tc; t += 4) {
    const float* p = OUT + ((size_t)t * 512 + b) * 512 + l * 8;
    float4 a = *(const float4*)p;
    float4 c = *(const float4*)(p + 4);
    acc[0] += a.x; acc[1] += a.y; acc[2] += a.z; acc[3] += a.w;
    acc[4] += c.x; acc[5] += c.y; acc[6] += c.z; acc[7] += c.w;
  }
#pragma unroll
  for (int i = 0; i < 8; ++i) sh[w][l * 8 + i] = acc[i];
  __syncthreads();
  for (int n = threadIdx.x; n < 512; n += 256) {
    TS[(size_t)b * 512 + n] +=
        (sh[0][n] + sh[1][n] + sh[2][n] + sh[3][n]) * (1.0f / (float)kT);
  }
}

// -------- Positional embedding projection ----------
__global__ __launch_bounds__(64) void posp_kernel(const float* __restrict__ Wp,
                                                  float* __restrict__ P) {
  __shared__ float emb[512];
  int jj = blockIdx.x;
  int t = threadIdx.x;
  float pos = (float)(kJ - 1 - jj);
#pragma unroll
  for (int r = 0; r < 8; ++r) {
    int d = t + r * 64;
    int i = (d < 256) ? d : d - 256;
    float invf = expf(-((float)(2 * i) * (1.0f / 512.0f)) * 9.210340371976184f);
    float si = pos * invf;
    emb[d] = (d < 256) ? sinf(si) : cosf(si);
  }
  __syncthreads();
  float acc = 0.f;
  for (int d = 0; d < 512; ++d) acc = fmaf(emb[d], Wp[d * 64 + t], acc);
  P[jj * 64 + t] = acc;
}

// -------- Attention (fp32 math), KV bf16 in, AV out as bf16 ----------
__global__ __launch_bounds__(128) void attn_kernel(
    const float* __restrict__ Q, const unsigned short* __restrict__ KV,
    const float* __restrict__ P, const float* __restrict__ U,
    const float* __restrict__ V, unsigned short* __restrict__ AV) {
  __shared__ float ks[kJ][32];
  __shared__ float vs[kJ][32];
  __shared__ float ps[32][kJ + 2];
  const int b = blockIdx.x, h = blockIdx.y;
  const int tid = threadIdx.x;
  for (int idx = tid; idx < kJ * 8; idx += 128) {
    int j = idx >> 3, seg = idx & 7;
    const unsigned short* src = KV + ((size_t)(j * kB + b)) * 128 + h * 32 + seg * 4;
    us4 kq = *(const us4*)src;
    us4 vq = *(const us4*)(src + 64);
#pragma unroll
    for (int e = 0; e < 4; ++e) {
      ks[j][seg * 4 + e] = b2f(kq[e]);
      vs[j][seg * 4 + e] = b2f(vq[e]);
    }
  }
  for (int idx = tid; idx < kJ * 8; idx += 128) {
    int j = idx >> 3, seg = idx & 7;
    float4 pq = *(const float4*)(P + j * 64 + h * 32 + seg * 4);
    ps[seg * 4 + 0][j] = pq.x;
    ps[seg * 4 + 1][j] = pq.y;
    ps[seg * 4 + 2][j] = pq.z;
    ps[seg * 4 + 3][j] = pq.w;
  }
  __syncthreads();
  const int i = tid;
  float qu[32], qv[32];
  const float* qp = Q + ((size_t)(i * kB + b)) * 64 + h * 32;
#pragma unroll
  for (int d = 0; d < 32; ++d) {
    float qd = qp[d];
    qu[d] = qd + U[h * 32 + d];
    qv[d] = qd + V[h * 32 + d];
  }
  float m = -INFINITY, l = 0.f, acc[32] = {};
  const float scale = 0.17677669529663687f;
  for (int j = 0; j <= i + kM; ++j) {
    float s = 0.f;
#pragma unroll
    for (int d = 0; d < 32; d += 4) {
      float4 k4 = *(const float4*)&ks[j][d];
      s = fmaf(qu[d + 0], k4.x, s);
      s = fmaf(qu[d + 1], k4.y, s);
      s = fmaf(qu[d + 2], k4.z, s);
      s = fmaf(qu[d + 3], k4.w, s);
    }
    int jj = j + (kT - 1) - i;
#pragma unroll
    for (int d = 0; d < 32; ++d) s = fmaf(qv[d], ps[d][jj], s);
    float ls = s * scale;
    float nm = fmaxf(m, ls);
    float w = __expf(ls - nm);
    float f = __expf(m - nm);
    l = l * f + w;
#pragma unroll
    for (int d = 0; d < 32; d += 4) {
      float4 v4 = *(const float4*)&vs[j][d];
      acc[d + 0] = fmaf(acc[d + 0], f, w * v4.x);
      acc[d + 1] = fmaf(acc[d + 1], f, w * v4.y);
      acc[d + 2] = fmaf(acc[d + 2], f, w * v4.z);
      acc[d + 3] = fmaf(acc[d + 3], f, w * v4.w);
    }
    m = nm;
  }
  float inv = 1.0f / l;
  unsigned short* o = AV + ((size_t)(i * kB + b)) * 64 + h * 32;
#pragma unroll
  for (int d = 0; d < 32; ++d) o[d] = bf16u(acc[d] * inv);
}

// -------- fp32 fallback GEMM for the small critic head --------
template <int ACTF, bool DUAL>
__global__ __launch_bounds__(256) void gemm_kernel(
    const float* __restrict__ A1, const float* __restrict__ Bm1, int K1,
    const float* __restrict__ A2, const float* __restrict__ Bm2, int K2,
    const float* __restrict__ bias, float* __restrict__ C, int Mrows, int N) {
  __shared__ float As[16][68];
  __shared__ float Bs[16][68];
  const int tid = threadIdx.x;
  const int tx = tid & 15, ty = tid >> 4;
  const int m0 = blockIdx.y * 64, n0 = blockIdx.x * 64;
  const int ar = tid >> 2, aseg = tid & 3;
  float acc[4][4] = {};
#pragma unroll
  for (int pass = 0; pass < (DUAL ? 2 : 1); ++pass) {
    const float* A = (DUAL && pass) ? A2 : A1;
    const float* Bm = (DUAL && pass) ? Bm2 : Bm1;
    const int K = (DUAL && pass) ? K2 : K1;
    for (int k0 = 0; k0 < K; k0 += 16) {
      {
        int row = m0 + ar;
        int kb = k0 + aseg * 4;
        float x0 = 0.f, x1 = 0.f, x2 = 0.f, x3 = 0.f;
        if (row < Mrows) {
          const float* ap = A + (size_t)row * K + kb;
          if (kb + 3 < K) {
            float4 t = *(const float4*)ap;
            x0 = t.x; x1 = t.y; x2 = t.z; x3 = t.w;
          } else {
            if (kb + 0 < K) x0 = ap[0];
            if (kb + 1 < K) x1 = ap[1];
            if (kb + 2 < K) x2 = ap[2];
          }
        }
        As[aseg * 4 + 0][ar] = x0;
        As[aseg * 4 + 1][ar] = x1;
        As[aseg * 4 + 2][ar] = x2;
        As[aseg * 4 + 3][ar] = x3;
      }
      {
        int krow = k0 + ty;
        int nb = n0 + tx * 4;
        float y0 = 0.f, y1 = 0.f, y2 = 0.f, y3 = 0.f;
        if (krow < K) {
          const float* bp = Bm + (size_t)krow * N + nb;
          if (nb + 3 < N) {
            float4 t = *(const float4*)bp;
            y0 = t.x; y1 = t.y; y2 = t.z; y3 = t.w;
          } else {
            if (nb + 0 < N) y0 = bp[0];
            if (nb + 1 < N) y1 = bp[1];
            if (nb + 2 < N) y2 = bp[2];
          }
        }
        *(float4*)&Bs[ty][tx * 4] = make_float4(y0, y1, y2, y3);
      }
      __syncthreads();
#pragma unroll
      for (int kk = 0; kk < 16; ++kk) {
        float a[4], bb[4];
        *(float4*)a = *(const float4*)&As[kk][ty * 4];
        *(float4*)bb = *(const float4*)&Bs[kk][tx * 4];
#pragma unroll
        for (int i = 0; i < 4; ++i)
#pragma unroll
          for (int j = 0; j < 4; ++j) acc[i][j] = fmaf(a[i], bb[j], acc[i][j]);
      }
      __syncthreads();
    }
  }
#pragma unroll
  for (int i = 0; i < 4; ++i) {
    int m = m0 + ty * 4 + i;
    if (m >= Mrows) continue;
#pragma unroll
    for (int j = 0; j < 4; ++j) {
      int n = n0 + tx * 4 + j;
      if (n >= N) continue;
      float val = acc[i][j];
      if (bias) val += bias[n];
      if (ACTF == 1) val = fmaxf(val, 0.f);
      C[(size_t)m * N + n] = val;
    }
  }
}

}  // namespace

extern "C" void kernel_launch(void* const* d_in, const int* in_sizes, int n_in,
                              void* d_out, int out_size, void* d_ws, size_t ws_size,
                              hipStream_t stream) {
  (void)in_sizes; (void)n_in; (void)out_size;
  const float* aug    = (const float*)d_in[0];
  const float* action = (const float*)d_in[1];
  const float* memory = (const float*)d_in[2];
  const float* W_q    = (const float*)d_in[3];
  const float* W_kv   = (const float*)d_in[4];
  const float* W_p    = (const float*)d_in[5];
  const float* W_out  = (const float*)d_in[6];
  const float* u      = (const float*)d_in[7];
  const float* v      = (const float*)d_in[8];
  const float* ln1_g  = (const float*)d_in[9];
  const float* ln1_b  = (const float*)d_in[10];
  const float* ln2_g  = (const float*)d_in[11];
  const float* ln2_b  = (const float*)d_in[12];
  const float* ff_W1  = (const float*)d_in[13];
  const float* ff_b1  = (const float*)d_in[14];
  const float* ff_W2  = (const float*)d_in[15];
  const float* ff_b2  = (const float*)d_in[16];
  const float* g1_W   = (const float*)d_in[17];
  const float* g1_b   = (const float*)d_in[18];
  const float* g2_W   = (const float*)d_in[19];
  const float* g2_b   = (const float*)d_in[20];
  const float* d1_W   = (const float*)d_in[21];
  const float* d1_b   = (const float*)d_in[22];
  const float* d2_W   = (const float*)d_in[23];
  const float* d2_b   = (const float*)d_in[24];
  const float* d3_W   = (const float*)d_in[25];
  const float* d3_b   = (const float*)d_in[26];
  const float* d4_W   = (const float*)d_in[27];
  const float* d4_b   = (const float*)d_in[28];
  float* out = (float*)d_out;

  // ---------------- workspace carve ----------------
  char* base = (char*)d_ws;
  auto alloc = [&](size_t bytes) -> char* {
    char* p = base;
    base += (bytes + 255) & ~(size_t)255;
    return p;
  };
  unsigned short* Wqt  = (unsigned short*)alloc((size_t)64 * 512 * 2);
  unsigned short* Wkvt = (unsigned short*)alloc((size_t)128 * 512 * 2);
  unsigned short* Wot  = (unsigned short*)alloc((size_t)512 * 64 * 2);
  unsigned short* Wf1t = (unsigned short*)alloc((size_t)64 * 512 * 2);
  unsigned short* Wf2t = (unsigned short*)alloc((size_t)512 * 64 * 2);
  unsigned short* G1t  = (unsigned short*)alloc((size_t)6 * 512 * 512 * 2);
  unsigned short* G2t  = (unsigned short*)alloc((size_t)6 * 512 * 512 * 2);
  unsigned short* Memb = (unsigned short*)alloc((size_t)3072 * 512 * 2);
  unsigned short* KVb  = (unsigned short*)alloc((size_t)kJ * kB * 128 * 2);
  float* Qb  = (float*)alloc((size_t)kTB * 64 * 4);
  unsigned short* AVb = (unsigned short*)alloc((size_t)kTB * 64 * 2);
  unsigned short* Xb  = (unsigned short*)alloc((size_t)kTB * kD * 2);  // raw aug bf16
  float* Pb  = (float*)alloc((size_t)kJ * 64 * 4);
  float* TSb = (float*)alloc((size_t)kB * kD * 4);
  float* H1b = (float*)alloc((size_t)kB * 1024 * 4);
  float* H2b = (float*)alloc((size_t)kB * 512 * 4);
  float* H3b = (float*)alloc((size_t)kB * 320 * 4);
  size_t fixedBytes = (size_t)(base - (char*)d_ws);
  const size_t ln1Bytes = (size_t)kTB * kD * 2;  // L1b overlaps chunk region
  int nch = 1;
  while (nch < 32) {
    size_t chunkBytes = (size_t)(kTB / nch) * 6272 + 4096;
    size_t reuse = chunkBytes > ln1Bytes ? chunkBytes : ln1Bytes;
    if (fixedBytes + reuse <= ws_size) break;
    nch <<= 1;
  }
  const int CR = kTB / nch;
  char* R = base;
  unsigned short* L1b = (unsigned short*)R;  // ln1(aug) bf16 (dead before chunks)
  char* rp = R;
  auto ralloc = [&](size_t bytes) -> char* {
    char* p = rp;
    rp += (bytes + 255) & ~(size_t)255;
    return p;
  };
  unsigned short* Ycb   = (unsigned short*)ralloc((size_t)CR * 512 * 2);
  unsigned short* RXcb  = (unsigned short*)ralloc((size_t)CR * 512 * 2);
  unsigned short* SRCcb = (unsigned short*)ralloc((size_t)CR * 512 * 2);
  unsigned short* LN2cb = (unsigned short*)ralloc((size_t)CR * 512 * 2);
  unsigned short* F1cb  = (unsigned short*)ralloc((size_t)CR * 64 * 2);
  float* Zpb            = (float*)ralloc((size_t)CR * 512 * 4);

  const float* np = nullptr;
  const int MG = CR / 128;  // m-groups per chunk (divisible by 8 for nch<=32)

  // -------- prep --------
  hipMemsetAsync(TSb, 0, (size_t)kB * kD * sizeof(float), stream);
  transp_kernel<<<dim3(2, 16, 1), 256, 0, stream>>>(W_q, Wqt, 512, 64);
  transp_kernel<<<dim3(4, 16, 1), 256, 0, stream>>>(W_kv, Wkvt, 512, 128);
  transp_kernel<<<dim3(16, 2, 1), 256, 0, stream>>>(W_out, Wot, 64, 512);
  transp_kernel<<<dim3(2, 16, 1), 256, 0, stream>>>(ff_W1, Wf1t, 512, 64);
  transp_kernel<<<dim3(16, 2, 1), 256, 0, stream>>>(ff_W2, Wf2t, 64, 512);
  transp_kernel<<<dim3(16, 16, 6), 256, 0, stream>>>(g1_W, G1t, 512, 512);
  transp_kernel<<<dim3(16, 16, 6), 256, 0, stream>>>(g2_W, G2t, 512, 512);
  conv_bf16_kernel<<<(3072 * 512 / 8 + 255) / 256, 256, 0, stream>>>(
      memory, Memb, (size_t)3072 * 512);
  // ln1(aug) -> L1b bf16 and raw aug -> Xb bf16 (one fp32 read)
  ln1_dual_kernel<<<kTB / 4, 256, 0, stream>>>(aug, ln1_g, ln1_b, L1b, Xb, kTB);
  // kv = [memory; ln1] @ W_kv  (bf16 out)
  mfma_gemm_bt<128, 1><<<dim3(1, 3072 / 128), 256, 0, stream>>>(
      Memb, Wkvt, 512, np, KVb, 128);
  mfma_gemm_bt<128, 1><<<dim3(1, kTB / 128), 256, 0, stream>>>(
      L1b, Wkvt, 512, np, KVb + (size_t)3072 * 128, 128);
  // q = ln1 @ W_q (fp32 out)
  mfma_gemm_bt<64, 0><<<dim3(1, kTB / 128), 256, 0, stream>>>(
      L1b, Wqt, 512, np, Qb, 64);
  posp_kernel<<<kJ, 64, 0, stream>>>(W_p, Pb);
  attn_kernel<<<dim3(kB, kH), 128, 0, stream>>>(Qb, KVb, Pb, u, v, AVb);

  for (int c = 0; c < nch; ++c) {
    const int R0 = c * CR;
    const unsigned short* Xc = Xb + (size_t)R0 * kD;
    // y1 = av @ W_out (bf16 out)
    mfma_gemm_bt<128, 1><<<dim3(4, MG), 256, 0, stream>>>(
        AVb + (size_t)R0 * 64, Wot, 64, np, Ycb, 512);
    // gate1: stage A (r + Zpre), stage B (h,z combine)
    mfma_gate_a<<<MG * 4, 512, 0, stream>>>(Ycb, Xc, G1t, g1_b, RXcb, Zpb);
    mfma_gate_b<false><<<MG * 2, 512, 0, stream>>>(
        Ycb, RXcb, Xc, G1t, g1_b, Zpb, SRCcb);
    // ln2 (bf16 in/out)
    ln_b16_kernel<<<CR / 4, 256, 0, stream>>>(SRCcb, ln2_g, ln2_b, LN2cb, CR);
    // ff1 = relu(ln2 @ ff_W1 + b1) (bf16 out)
    mfma_gemm_bt<64, 2><<<dim3(1, MG), 256, 0, stream>>>(
        LN2cb, Wf1t, 512, ff_b1, F1cb, 64);
    // y2 = ff1 @ ff_W2 + b2 (bf16 out)
    mfma_gemm_bt<128, 3><<<dim3(4, MG), 256, 0, stream>>>(
        F1cb, Wf2t, 64, ff_b2, Ycb, 512);
    // gate2: stage A, stage B (fp32 out in-place over Zpb), then pool-reduce
    mfma_gate_a<<<MG * 4, 512, 0, stream>>>(Ycb, SRCcb, G2t, g2_b, RXcb, Zpb);
    mfma_gate_b<true><<<MG * 2, 512, 0, stream>>>(
        Ycb, RXcb, SRCcb, G2t, g2_b, Zpb, nullptr);
    pool_kernel<<<kB, 256, 0, stream>>>(Zpb, TSb, CR / 512);
  }

  // critic head (fp32)
  gemm_kernel<1, false><<<dim3(16, kB / 64), 256, 0, stream>>>(
      TSb, d1_W, 512, np, np, 0, d1_b, H1b, kB, 1024);
  gemm_kernel<1, true><<<dim3(8, kB / 64), 256, 0, stream>>>(
      H1b, d2_W, 1024, action, d2_W + (size_t)1024 * 512, 64, d2_b, H2b, kB, 512);
  gemm_kernel<1, false><<<dim3(5, kB / 64), 256, 0, stream>>>(
      H2b, d3_W, 512, np, np, 0, d3_b, H3b, kB, 300);
  gemm_kernel<1, false><<<dim3(1, kB / 64), 256, 0, stream>>>(
      H3b, d4_W, 300, np, np, 0, d4_b, out, kB, 1);
}

// Round 2
// 1550.412 us; speedup vs baseline: 1.0858x; 1.0858x over previous
//
#include <hip/hip_runtime.h>
#include <math.h>

namespace {

constexpr int kT = 128, kB = 512, kD = 512, kM = 6, kH = 2;
constexpr int kJ = kT + kM;          // 134
constexpr float kBG = 0.1f;
constexpr int kTB = kT * kB;         // 65536 rows
constexpr int kBK = 32;              // K-tile for MFMA kernels

typedef __attribute__((ext_vector_type(8))) short bf16x8;
typedef __attribute__((ext_vector_type(4))) float f32x4;
typedef __attribute__((ext_vector_type(8))) unsigned short us8;
typedef __attribute__((ext_vector_type(4))) unsigned short us4;

__device__ __forceinline__ float sigmoidf_(float x) {
  return 1.0f / (1.0f + __expf(-x));
}

__device__ __forceinline__ unsigned short bf16u(float f) {
  union { float f; unsigned u; } c; c.f = f;
  unsigned r = c.u + 0x7fffu + ((c.u >> 16) & 1u);
  return (unsigned short)(r >> 16);
}

__device__ __forceinline__ float b2f(unsigned short u) {
  union { unsigned u; float f; } c; c.u = (unsigned)u << 16;
  return c.f;
}

__device__ __forceinline__ void gl_lds16(const void* g, void* l) {
  __builtin_amdgcn_global_load_lds(
      (const __attribute__((address_space(1))) unsigned int*)g,
      (__attribute__((address_space(3))) unsigned int*)l, 16, 0, 0);
}

// ---- transpose + cast: W fp32 [K][N] -> Wt bf16 [N][K]; dims mult of 32 ----
__global__ __launch_bounds__(256) void transp_kernel(const float* __restrict__ W,
                                                     unsigned short* __restrict__ Wt,
                                                     int K, int N) {
  __shared__ float t[32][33];
  const int n0 = blockIdx.x * 32, k0 = blockIdx.y * 32;
  const float* Wb = W + (size_t)blockIdx.z * K * N;
  unsigned short* Wtb = Wt + (size_t)blockIdx.z * K * N;
  int tx = threadIdx.x & 31, ty = threadIdx.x >> 5;  // 32 x 8
#pragma unroll
  for (int r = 0; r < 32; r += 8)
    t[ty + r][tx] = Wb[(size_t)(k0 + ty + r) * N + n0 + tx];
  __syncthreads();
#pragma unroll
  for (int r = 0; r < 32; r += 8)
    Wtb[(size_t)(n0 + ty + r) * K + k0 + tx] = bf16u(t[tx][ty + r]);
}

// ---- fp32 -> bf16 elementwise (n multiple of 8) ----
__global__ __launch_bounds__(256) void conv_bf16_kernel(const float* __restrict__ in,
                                                        unsigned short* __restrict__ outb,
                                                        size_t n) {
  size_t idx = ((size_t)blockIdx.x * 256 + threadIdx.x) * 8;
  if (idx >= n) return;
  float4 a = *(const float4*)(in + idx);
  float4 c = *(const float4*)(in + idx + 4);
  us8 o;
  o[0] = bf16u(a.x); o[1] = bf16u(a.y); o[2] = bf16u(a.z); o[3] = bf16u(a.w);
  o[4] = bf16u(c.x); o[5] = bf16u(c.y); o[6] = bf16u(c.z); o[7] = bf16u(c.w);
  *(us8*)(outb + idx) = o;
}

// ---- LN1 dual-output: LN(x) -> bf16 AND raw x -> bf16, one fp32 read ----
__global__ __launch_bounds__(256) void ln1_dual_kernel(const float* __restrict__ in,
                                                       const float* __restrict__ g,
                                                       const float* __restrict__ b,
                                                       unsigned short* __restrict__ outLN,
                                                       unsigned short* __restrict__ outRaw,
                                                       int nrows) {
  int wave = threadIdx.x >> 6, lane = threadIdx.x & 63;
  int row = blockIdx.x * 4 + wave;
  if (row >= nrows) return;
  const float* p = in + (size_t)row * kD + lane * 8;
  float4 a = *(const float4*)p;
  float4 c = *(const float4*)(p + 4);
  float v[8] = {a.x, a.y, a.z, a.w, c.x, c.y, c.z, c.w};
  float s = 0.f;
#pragma unroll
  for (int i = 0; i < 8; ++i) s += v[i];
#pragma unroll
  for (int off = 32; off; off >>= 1) s += __shfl_xor(s, off);
  float mu = s * (1.0f / 512.0f);
  float q = 0.f;
#pragma unroll
  for (int i = 0; i < 8; ++i) { float d = v[i] - mu; q += d * d; }
#pragma unroll
  for (int off = 32; off; off >>= 1) q += __shfl_xor(q, off);
  float rstd = rsqrtf(q * (1.0f / 512.0f) + 1e-5f);
  us8 oln, oraw;
#pragma unroll
  for (int i = 0; i < 8; ++i) {
    int col = lane * 8 + i;
    oln[i] = bf16u((v[i] - mu) * rstd * g[col] + b[col]);
    oraw[i] = bf16u(v[i]);
  }
  size_t off8 = (size_t)row * kD + lane * 8;
  *(us8*)(outLN + off8) = oln;
  *(us8*)(outRaw + off8) = oraw;
}

// ---- LN with bf16 input -> bf16 out ----
__global__ __launch_bounds__(256) void ln_b16_kernel(const unsigned short* __restrict__ in,
                                                     const float* __restrict__ g,
                                                     const float* __restrict__ b,
                                                     unsigned short* __restrict__ outb,
                                                     int nrows) {
  int wave = threadIdx.x >> 6, lane = threadIdx.x & 63;
  int row = blockIdx.x * 4 + wave;
  if (row >= nrows) return;
  us8 iv = *(const us8*)(in + (size_t)row * kD + lane * 8);
  float v[8];
#pragma unroll
  for (int i = 0; i < 8; ++i) v[i] = b2f(iv[i]);
  float s = 0.f;
#pragma unroll
  for (int i = 0; i < 8; ++i) s += v[i];
#pragma unroll
  for (int off = 32; off; off >>= 1) s += __shfl_xor(s, off);
  float mu = s * (1.0f / 512.0f);
  float q = 0.f;
#pragma unroll
  for (int i = 0; i < 8; ++i) { float d = v[i] - mu; q += d * d; }
#pragma unroll
  for (int off = 32; off; off >>= 1) q += __shfl_xor(q, off);
  float rstd = rsqrtf(q * (1.0f / 512.0f) + 1e-5f);
  us8 o;
#pragma unroll
  for (int i = 0; i < 8; ++i) {
    int col = lane * 8 + i;
    o[i] = bf16u((v[i] - mu) * rstd * g[col] + b[col]);
  }
  *(us8*)(outb + (size_t)row * kD + lane * 8) = o;
}

// ============ MFMA GEMM, B^T input: C[M][N] = A[M][K] @ Bt[N][K]^T ==========
// 128 x TN tile, 256 threads (4 waves), BK=32, global_load_lds width 16.
// T3 2-phase: double-buffered LDS, stage(next) issued BEFORE compute(cur),
// ONE barrier per K-step (vmcnt(0) drain lands after the MFMA work).
// EPI: 0 = fp32 out, 1 = bf16 out, 2 = bias+relu+bf16, 3 = bias+bf16.
template <int TN, int EPI>
__global__ __launch_bounds__(256) void mfma_gemm_bt(
    const unsigned short* __restrict__ A, const unsigned short* __restrict__ Bt,
    int K, const float* __restrict__ bias, void* __restrict__ Cv, int N) {
  constexpr int MI = (TN == 128) ? 4 : 2;
  constexpr int NJ = 4;
  constexpr int BCH = TN * 64 / 1024;
  __shared__ __align__(16) unsigned short As[2][128 * kBK];
  __shared__ __align__(16) unsigned short Bs[2][TN * kBK];
  const int tid = threadIdx.x;
  const int lane = tid & 63, wv = tid >> 6;
  const int ml = lane & 15, qd = lane >> 4;
  const int m0 = blockIdx.y * 128, n0 = blockIdx.x * TN;
  const int mw0 = (TN == 128) ? (wv >> 1) * 64 : wv * 32;
  const int nw0 = (TN == 128) ? (wv & 1) * 64 : 0;
  const size_t ldA = (size_t)K * 2, ldB = (size_t)K * 2;
  const char* Ab = (const char*)A + (size_t)m0 * ldA;
  const char* Bb = (const char*)Bt + (size_t)n0 * ldB;
  auto stg = [&](int k0, int buf) {
#pragma unroll
    for (int c = wv; c < 8; c += 4) {
      int fb = c * 1024 + lane * 16;
      gl_lds16(Ab + (size_t)(fb >> 6) * ldA + (fb & 63) + (size_t)k0 * 2,
               (char*)As[buf] + c * 1024);
    }
#pragma unroll
    for (int c = wv; c < BCH; c += 4) {
      int fb = c * 1024 + lane * 16;
      gl_lds16(Bb + (size_t)(fb >> 6) * ldB + (fb & 63) + (size_t)k0 * 2,
               (char*)Bs[buf] + c * 1024);
    }
  };
  f32x4 acc[MI][NJ];
#pragma unroll
  for (int i = 0; i < MI; ++i)
#pragma unroll
    for (int j = 0; j < NJ; ++j) acc[i][j] = (f32x4)0.f;
  stg(0, 0);
  __syncthreads();
  int cur = 0;
  for (int k0 = 0; k0 < K; k0 += kBK) {
    if (k0 + kBK < K) stg(k0 + kBK, cur ^ 1);
    bf16x8 af[MI], bfr[NJ];
#pragma unroll
    for (int i = 0; i < MI; ++i)
      af[i] = *(const bf16x8*)(As[cur] + (mw0 + i * 16 + ml) * kBK + qd * 8);
#pragma unroll
    for (int j = 0; j < NJ; ++j)
      bfr[j] = *(const bf16x8*)(Bs[cur] + (nw0 + j * 16 + ml) * kBK + qd * 8);
#pragma unroll
    for (int i = 0; i < MI; ++i)
#pragma unroll
      for (int j = 0; j < NJ; ++j)
        acc[i][j] = __builtin_amdgcn_mfma_f32_16x16x32_bf16(af[i], bfr[j], acc[i][j], 0, 0, 0);
    __syncthreads();
    cur ^= 1;
  }
#pragma unroll
  for (int i = 0; i < MI; ++i)
#pragma unroll
    for (int j = 0; j < NJ; ++j)
#pragma unroll
      for (int r = 0; r < 4; ++r) {
        int m = m0 + mw0 + i * 16 + qd * 4 + r;
        int n = n0 + nw0 + j * 16 + ml;
        float val = acc[i][j][r];
        if (EPI >= 2) val += bias[n];
        if (EPI == 2) val = fmaxf(val, 0.f);
        size_t idx = (size_t)m * N + n;
        if (EPI == 0) ((float*)Cv)[idx] = val;
        else ((unsigned short*)Cv)[idx] = bf16u(val);
      }
}

// XCD swizzle: 1-D grid of MG*NB blocks. All NB n-blocks of one m-group land
// on the SAME XCD in ADJACENT dispatch slots -> A tile fetched once into that
// XCD's L2 and shared (perf-only heuristic; correctness never depends on it).
template <int NBLOG>
__device__ __forceinline__ void xcd_decode(int& m0, int& n0, int tileN) {
  const int L = blockIdx.x;
  const int xcd = L & 7;
  const int s = L >> 3;
  const int mgPerX = (int)(gridDim.x >> (3 + NBLOG));
  const int mg = xcd * mgPerX + (s >> NBLOG);
  const int nb = s & ((1 << NBLOG) - 1);
  m0 = mg * 128;
  n0 = nb * tileN;
}

// ====== gate r: 128x256 tile, 512 threads (8 waves, 2M x 4N), per-wave 64x64.
// T3 2-phase double-buffered. acc = Y@W0t^T + X@W1t^T (2 passes, cross-pass
// prefetch); RX = bf16(sigmoid(acc+b0+b1)*x). LDS 48 KB.
__global__ __launch_bounds__(512, 4) void mfma_gate_r(
    const unsigned short* __restrict__ Yb, const unsigned short* __restrict__ Xb,
    const unsigned short* __restrict__ Wt, const float* __restrict__ gb,
    unsigned short* __restrict__ RX) {
  __shared__ __align__(16) unsigned short As[2][128 * kBK];   // 16 KB
  __shared__ __align__(16) unsigned short Bs[2][256 * kBK];   // 32 KB
  const int tid = threadIdx.x;
  const int lane = tid & 63, wv = tid >> 6;  // 8 waves
  const int ml = lane & 15, qd = lane >> 4;
  int m0, n0;
  xcd_decode<1>(m0, n0, 256);
  const int mw0 = (wv & 1) * 64, nw0 = (wv >> 1) * 64;
  const size_t ld = (size_t)kD * 2;
  const size_t DD = (size_t)kD * kD;
  const char* Abp[2], *Bbp[2];
  {
    const unsigned short* Ap[2] = {Yb, Xb};
#pragma unroll
    for (int p = 0; p < 2; ++p) {
      Abp[p] = (const char*)Ap[p] + (size_t)m0 * ld;
      Bbp[p] = (const char*)(Wt + (size_t)p * DD) + (size_t)n0 * ld;
    }
  }
  auto stg = [&](const char* Ab, const char* Bb, int k0, int buf) {
    {
      int fb = wv * 1024 + lane * 16;
      gl_lds16(Ab + (size_t)(fb >> 6) * ld + (fb & 63) + (size_t)k0 * 2,
               (char*)As[buf] + wv * 1024);
    }
#pragma unroll
    for (int c = wv; c < 16; c += 8) {
      int fb = c * 1024 + lane * 16;
      gl_lds16(Bb + (size_t)(fb >> 6) * ld + (fb & 63) + (size_t)k0 * 2,
               (char*)Bs[buf] + c * 1024);
    }
  };
  f32x4 acc[4][4];
#pragma unroll
  for (int i = 0; i < 4; ++i)
#pragma unroll
    for (int j = 0; j < 4; ++j) acc[i][j] = (f32x4)0.f;
  stg(Abp[0], Bbp[0], 0, 0);
  __syncthreads();
  int cur = 0;
#pragma unroll
  for (int p = 0; p < 2; ++p) {
    for (int k = 0; k < 16; ++k) {
      if (k < 15) stg(Abp[p], Bbp[p], (k + 1) * kBK, cur ^ 1);
      else if (p < 1) stg(Abp[p + 1], Bbp[p + 1], 0, cur ^ 1);
      bf16x8 af[4], bfr[4];
#pragma unroll
      for (int i = 0; i < 4; ++i)
        af[i] = *(const bf16x8*)(As[cur] + (mw0 + i * 16 + ml) * kBK + qd * 8);
#pragma unroll
      for (int j = 0; j < 4; ++j)
        bfr[j] = *(const bf16x8*)(Bs[cur] + (nw0 + j * 16 + ml) * kBK + qd * 8);
#pragma unroll
      for (int i = 0; i < 4; ++i)
#pragma unroll
        for (int j = 0; j < 4; ++j)
          acc[i][j] = __builtin_amdgcn_mfma_f32_16x16x32_bf16(af[i], bfr[j], acc[i][j], 0, 0, 0);
      __syncthreads();
      cur ^= 1;
    }
  }
#pragma unroll
  for (int i = 0; i < 4; ++i)
#pragma unroll
    for (int j = 0; j < 4; ++j)
#pragma unroll
      for (int r = 0; r < 4; ++r) {
        int m = m0 + mw0 + i * 16 + qd * 4 + r;
        int n = n0 + nw0 + j * 16 + ml;
        float rg = sigmoidf_(acc[i][j][r] + gb[n] + gb[kD + n]);
        size_t idx = (size_t)m * kD + n;
        RX[idx] = bf16u(rg * b2f(Xb[idx]));
      }
}

// ====== gate h+z: 128x128 tile, 512 threads (8 waves, 4M x 2N), per-wave
// 32x64; T3 2-phase double-buffered; 4 passes with cross-pass prefetch.
// accH = Y@W4 + RX@W5 ; accZ = Y@W2 + X@W3.
// out = (1-z)*x + z*tanh(accH+b4+b5), z = sigmoid(accZ+b2+b3-BG). LDS 32 KB.
// POOL=false: OUTb bf16. POOL=true: atomic mean-pool into TS.
template <bool POOL>
__global__ __launch_bounds__(512, 4) void mfma_gate_hz(
    const unsigned short* __restrict__ Yb, const unsigned short* __restrict__ RXb,
    const unsigned short* __restrict__ Xb, const unsigned short* __restrict__ Wt,
    const float* __restrict__ gb, unsigned short* __restrict__ OUTb,
    float* __restrict__ TS, int rowoff) {
  __shared__ __align__(16) unsigned short As[2][128 * kBK];  // 16 KB
  __shared__ __align__(16) unsigned short Bs[2][128 * kBK];  // 16 KB
  const int tid = threadIdx.x;
  const int lane = tid & 63, wv = tid >> 6;  // 8 waves
  const int ml = lane & 15, qd = lane >> 4;
  int m0, n0;
  xcd_decode<2>(m0, n0, 128);
  const int mw0 = (wv & 3) * 32, nw0 = (wv >> 2) * 64;
  const size_t ld = (size_t)kD * 2;
  const size_t DD = (size_t)kD * kD;
  f32x4 accH[2][4], accZ[2][4];
#pragma unroll
  for (int i = 0; i < 2; ++i)
#pragma unroll
    for (int j = 0; j < 4; ++j) { accH[i][j] = (f32x4)0.f; accZ[i][j] = (f32x4)0.f; }
  const char* Abp[4], *Bbp[4];
  {
    const unsigned short* Ap[4] = {Yb, RXb, Yb, Xb};
    const int wsel[4] = {4, 5, 2, 3};
#pragma unroll
    for (int p = 0; p < 4; ++p) {
      Abp[p] = (const char*)Ap[p] + (size_t)m0 * ld;
      Bbp[p] = (const char*)(Wt + (size_t)wsel[p] * DD) + (size_t)n0 * ld;
    }
  }
  auto stg = [&](const char* Ab, const char* Bb, int k0, int buf) {
    int fb = wv * 1024 + lane * 16;
    size_t go = (size_t)(fb >> 6) * ld + (fb & 63) + (size_t)k0 * 2;
    gl_lds16(Ab + go, (char*)As[buf] + wv * 1024);
    gl_lds16(Bb + go, (char*)Bs[buf] + wv * 1024);
  };
  stg(Abp[0], Bbp[0], 0, 0);
  __syncthreads();
  int cur = 0;
#pragma unroll
  for (int p = 0; p < 4; ++p) {
    f32x4 (*acc)[4] = (p < 2) ? accH : accZ;
    for (int k = 0; k < 16; ++k) {
      if (k < 15) stg(Abp[p], Bbp[p], (k + 1) * kBK, cur ^ 1);
      else if (p < 3) stg(Abp[p + 1], Bbp[p + 1], 0, cur ^ 1);
      bf16x8 af[2], bfr[4];
#pragma unroll
      for (int i = 0; i < 2; ++i)
        af[i] = *(const bf16x8*)(As[cur] + (mw0 + i * 16 + ml) * kBK + qd * 8);
#pragma unroll
      for (int j = 0; j < 4; ++j)
        bfr[j] = *(const bf16x8*)(Bs[cur] + (nw0 + j * 16 + ml) * kBK + qd * 8);
#pragma unroll
      for (int i = 0; i < 2; ++i)
#pragma unroll
        for (int j = 0; j < 4; ++j)
          acc[i][j] = __builtin_amdgcn_mfma_f32_16x16x32_bf16(af[i], bfr[j], acc[i][j], 0, 0, 0);
      __syncthreads();
      cur ^= 1;
    }
  }
#pragma unroll
  for (int i = 0; i < 2; ++i)
#pragma unroll
    for (int j = 0; j < 4; ++j)
#pragma unroll
      for (int r = 0; r < 4; ++r) {
        int m = m0 + mw0 + i * 16 + qd * 4 + r;
        int n = n0 + nw0 + j * 16 + ml;
        float z = sigmoidf_(accZ[i][j][r] + gb[2 * kD + n] + gb[3 * kD + n] - kBG);
        float hc = tanhf(accH[i][j][r] + gb[4 * kD + n] + gb[5 * kD + n]);
        size_t idx = (size_t)m * kD + n;
        float val = (1.0f - z) * b2f(Xb[idx]) + z * hc;
        if (POOL) {
          int b = (rowoff + m) & (kB - 1);
          atomicAdd(TS + (size_t)b * kD + n, val * (1.0f / kT));
        } else {
          OUTb[idx] = bf16u(val);
        }
      }
}

// -------- Positional embedding projection ----------
__global__ __launch_bounds__(64) void posp_kernel(const float* __restrict__ Wp,
                                                  float* __restrict__ P) {
  __shared__ float emb[512];
  int jj = blockIdx.x;
  int t = threadIdx.x;
  float pos = (float)(kJ - 1 - jj);
#pragma unroll
  for (int r = 0; r < 8; ++r) {
    int d = t + r * 64;
    int i = (d < 256) ? d : d - 256;
    float invf = expf(-((float)(2 * i) * (1.0f / 512.0f)) * 9.210340371976184f);
    float si = pos * invf;
    emb[d] = (d < 256) ? sinf(si) : cosf(si);
  }
  __syncthreads();
  float acc = 0.f;
  for (int d = 0; d < 512; ++d) acc = fmaf(emb[d], Wp[d * 64 + t], acc);
  P[jj * 64 + t] = acc;
}

// -------- Attention (fp32 math), KV bf16 in, AV out as bf16 ----------
__global__ __launch_bounds__(128) void attn_kernel(
    const float* __restrict__ Q, const unsigned short* __restrict__ KV,
    const float* __restrict__ P, const float* __restrict__ U,
    const float* __restrict__ V, unsigned short* __restrict__ AV) {
  __shared__ float ks[kJ][32];
  __shared__ float vs[kJ][32];
  __shared__ float ps[32][kJ + 2];
  const int b = blockIdx.x, h = blockIdx.y;
  const int tid = threadIdx.x;
  for (int idx = tid; idx < kJ * 8; idx += 128) {
    int j = idx >> 3, seg = idx & 7;
    const unsigned short* src = KV + ((size_t)(j * kB + b)) * 128 + h * 32 + seg * 4;
    us4 kq = *(const us4*)src;
    us4 vq = *(const us4*)(src + 64);
#pragma unroll
    for (int e = 0; e < 4; ++e) {
      ks[j][seg * 4 + e] = b2f(kq[e]);
      vs[j][seg * 4 + e] = b2f(vq[e]);
    }
  }
  for (int idx = tid; idx < kJ * 8; idx += 128) {
    int j = idx >> 3, seg = idx & 7;
    float4 pq = *(const float4*)(P + j * 64 + h * 32 + seg * 4);
    ps[seg * 4 + 0][j] = pq.x;
    ps[seg * 4 + 1][j] = pq.y;
    ps[seg * 4 + 2][j] = pq.z;
    ps[seg * 4 + 3][j] = pq.w;
  }
  __syncthreads();
  const int i = tid;
  float qu[32], qv[32];
  const float* qp = Q + ((size_t)(i * kB + b)) * 64 + h * 32;
#pragma unroll
  for (int d = 0; d < 32; ++d) {
    float qd = qp[d];
    qu[d] = qd + U[h * 32 + d];
    qv[d] = qd + V[h * 32 + d];
  }
  float m = -INFINITY, l = 0.f, acc[32] = {};
  const float scale = 0.17677669529663687f;
  for (int j = 0; j <= i + kM; ++j) {
    float s = 0.f;
#pragma unroll
    for (int d = 0; d < 32; d += 4) {
      float4 k4 = *(const float4*)&ks[j][d];
      s = fmaf(qu[d + 0], k4.x, s);
      s = fmaf(qu[d + 1], k4.y, s);
      s = fmaf(qu[d + 2], k4.z, s);
      s = fmaf(qu[d + 3], k4.w, s);
    }
    int jj = j + (kT - 1) - i;
#pragma unroll
    for (int d = 0; d < 32; ++d) s = fmaf(qv[d], ps[d][jj], s);
    float ls = s * scale;
    float nm = fmaxf(m, ls);
    float w = __expf(ls - nm);
    float f = __expf(m - nm);
    l = l * f + w;
#pragma unroll
    for (int d = 0; d < 32; d += 4) {
      float4 v4 = *(const float4*)&vs[j][d];
      acc[d + 0] = fmaf(acc[d + 0], f, w * v4.x);
      acc[d + 1] = fmaf(acc[d + 1], f, w * v4.y);
      acc[d + 2] = fmaf(acc[d + 2], f, w * v4.z);
      acc[d + 3] = fmaf(acc[d + 3], f, w * v4.w);
    }
    m = nm;
  }
  float inv = 1.0f / l;
  unsigned short* o = AV + ((size_t)(i * kB + b)) * 64 + h * 32;
#pragma unroll
  for (int d = 0; d < 32; ++d) o[d] = bf16u(acc[d] * inv);
}

// -------- fp32 fallback GEMM for the small critic head --------
template <int ACTF, bool DUAL>
__global__ __launch_bounds__(256) void gemm_kernel(
    const float* __restrict__ A1, const float* __restrict__ Bm1, int K1,
    const float* __restrict__ A2, const float* __restrict__ Bm2, int K2,
    const float* __restrict__ bias, float* __restrict__ C, int Mrows, int N) {
  __shared__ float As[16][68];
  __shared__ float Bs[16][68];
  const int tid = threadIdx.x;
  const int tx = tid & 15, ty = tid >> 4;
  const int m0 = blockIdx.y * 64, n0 = blockIdx.x * 64;
  const int ar = tid >> 2, aseg = tid & 3;
  float acc[4][4] = {};
#pragma unroll
  for (int pass = 0; pass < (DUAL ? 2 : 1); ++pass) {
    const float* A = (DUAL && pass) ? A2 : A1;
    const float* Bm = (DUAL && pass) ? Bm2 : Bm1;
    const int K = (DUAL && pass) ? K2 : K1;
    for (int k0 = 0; k0 < K; k0 += 16) {
      {
        int row = m0 + ar;
        int kb = k0 + aseg * 4;
        float x0 = 0.f, x1 = 0.f, x2 = 0.f, x3 = 0.f;
        if (row < Mrows) {
          const float* ap = A + (size_t)row * K + kb;
          if (kb + 3 < K) {
            float4 t = *(const float4*)ap;
            x0 = t.x; x1 = t.y; x2 = t.z; x3 = t.w;
          } else {
            if (kb + 0 < K) x0 = ap[0];
            if (kb + 1 < K) x1 = ap[1];
            if (kb + 2 < K) x2 = ap[2];
          }
        }
        As[aseg * 4 + 0][ar] = x0;
        As[aseg * 4 + 1][ar] = x1;
        As[aseg * 4 + 2][ar] = x2;
        As[aseg * 4 + 3][ar] = x3;
      }
      {
        int krow = k0 + ty;
        int nb = n0 + tx * 4;
        float y0 = 0.f, y1 = 0.f, y2 = 0.f, y3 = 0.f;
        if (krow < K) {
          const float* bp = Bm + (size_t)krow * N + nb;
          if (nb + 3 < N) {
            float4 t = *(const float4*)bp;
            y0 = t.x; y1 = t.y; y2 = t.z; y3 = t.w;
          } else {
            if (nb + 0 < N) y0 = bp[0];
            if (nb + 1 < N) y1 = bp[1];
            if (nb + 2 < N) y2 = bp[2];
          }
        }
        *(float4*)&Bs[ty][tx * 4] = make_float4(y0, y1, y2, y3);
      }
      __syncthreads();
#pragma unroll
      for (int kk = 0; kk < 16; ++kk) {
        float a[4], bb[4];
        *(float4*)a = *(const float4*)&As[kk][ty * 4];
        *(float4*)bb = *(const float4*)&Bs[kk][tx * 4];
#pragma unroll
        for (int i = 0; i < 4; ++i)
#pragma unroll
          for (int j = 0; j < 4; ++j) acc[i][j] = fmaf(a[i], bb[j], acc[i][j]);
      }
      __syncthreads();
    }
  }
#pragma unroll
  for (int i = 0; i < 4; ++i) {
    int m = m0 + ty * 4 + i;
    if (m >= Mrows) continue;
#pragma unroll
    for (int j = 0; j < 4; ++j) {
      int n = n0 + tx * 4 + j;
      if (n >= N) continue;
      float val = acc[i][j];
      if (bias) val += bias[n];
      if (ACTF == 1) val = fmaxf(val, 0.f);
      C[(size_t)m * N + n] = val;
    }
  }
}

}  // namespace

extern "C" void kernel_launch(void* const* d_in, const int* in_sizes, int n_in,
                              void* d_out, int out_size, void* d_ws, size_t ws_size,
                              hipStream_t stream) {
  (void)in_sizes; (void)n_in; (void)out_size;
  const float* aug    = (const float*)d_in[0];
  const float* action = (const float*)d_in[1];
  const float* memory = (const float*)d_in[2];
  const float* W_q    = (const float*)d_in[3];
  const float* W_kv   = (const float*)d_in[4];
  const float* W_p    = (const float*)d_in[5];
  const float* W_out  = (const float*)d_in[6];
  const float* u      = (const float*)d_in[7];
  const float* v      = (const float*)d_in[8];
  const float* ln1_g  = (const float*)d_in[9];
  const float* ln1_b  = (const float*)d_in[10];
  const float* ln2_g  = (const float*)d_in[11];
  const float* ln2_b  = (const float*)d_in[12];
  const float* ff_W1  = (const float*)d_in[13];
  const float* ff_b1  = (const float*)d_in[14];
  const float* ff_W2  = (const float*)d_in[15];
  const float* ff_b2  = (const float*)d_in[16];
  const float* g1_W   = (const float*)d_in[17];
  const float* g1_b   = (const float*)d_in[18];
  const float* g2_W   = (const float*)d_in[19];
  const float* g2_b   = (const float*)d_in[20];
  const float* d1_W   = (const float*)d_in[21];
  const float* d1_b   = (const float*)d_in[22];
  const float* d2_W   = (const float*)d_in[23];
  const float* d2_b   = (const float*)d_in[24];
  const float* d3_W   = (const float*)d_in[25];
  const float* d3_b   = (const float*)d_in[26];
  const float* d4_W   = (const float*)d_in[27];
  const float* d4_b   = (const float*)d_in[28];
  float* out = (float*)d_out;

  // ---------------- workspace carve ----------------
  char* base = (char*)d_ws;
  auto alloc = [&](size_t bytes) -> char* {
    char* p = base;
    base += (bytes + 255) & ~(size_t)255;
    return p;
  };
  unsigned short* Wqt  = (unsigned short*)alloc((size_t)64 * 512 * 2);
  unsigned short* Wkvt = (unsigned short*)alloc((size_t)128 * 512 * 2);
  unsigned short* Wot  = (unsigned short*)alloc((size_t)512 * 64 * 2);
  unsigned short* Wf1t = (unsigned short*)alloc((size_t)64 * 512 * 2);
  unsigned short* Wf2t = (unsigned short*)alloc((size_t)512 * 64 * 2);
  unsigned short* G1t  = (unsigned short*)alloc((size_t)6 * 512 * 512 * 2);
  unsigned short* G2t  = (unsigned short*)alloc((size_t)6 * 512 * 512 * 2);
  unsigned short* Memb = (unsigned short*)alloc((size_t)3072 * 512 * 2);
  unsigned short* KVb  = (unsigned short*)alloc((size_t)kJ * kB * 128 * 2);
  float* Qb  = (float*)alloc((size_t)kTB * 64 * 4);
  unsigned short* AVb = (unsigned short*)alloc((size_t)kTB * 64 * 2);
  unsigned short* Xb  = (unsigned short*)alloc((size_t)kTB * kD * 2);  // raw aug bf16
  float* Pb  = (float*)alloc((size_t)kJ * 64 * 4);
  float* TSb = (float*)alloc((size_t)kB * kD * 4);
  float* H1b = (float*)alloc((size_t)kB * 1024 * 4);
  float* H2b = (float*)alloc((size_t)kB * 512 * 4);
  float* H3b = (float*)alloc((size_t)kB * 320 * 4);
  size_t fixedBytes = (size_t)(base - (char*)d_ws);
  const size_t ln1Bytes = (size_t)kTB * kD * 2;  // L1b overlaps chunk region
  int nch = 1;
  while (nch < 32) {
    size_t chunkBytes = (size_t)(kTB / nch) * 4224 + 4096;
    size_t reuse = chunkBytes > ln1Bytes ? chunkBytes : ln1Bytes;
    if (fixedBytes + reuse <= ws_size) break;
    nch <<= 1;
  }
  const int CR = kTB / nch;
  char* R = base;
  unsigned short* L1b = (unsigned short*)R;  // ln1(aug) bf16 (dead before chunks)
  char* rp = R;
  auto ralloc = [&](size_t bytes) -> char* {
    char* p = rp;
    rp += (bytes + 255) & ~(size_t)255;
    return p;
  };
  unsigned short* Ycb   = (unsigned short*)ralloc((size_t)CR * 512 * 2);
  unsigned short* RXcb  = (unsigned short*)ralloc((size_t)CR * 512 * 2);
  unsigned short* SRCcb = (unsigned short*)ralloc((size_t)CR * 512 * 2);
  unsigned short* LN2cb = (unsigned short*)ralloc((size_t)CR * 512 * 2);
  unsigned short* F1cb  = (unsigned short*)ralloc((size_t)CR * 64 * 2);

  const float* np = nullptr;
  const int MG = CR / 128;  // m-groups per chunk (divisible by 8 for nch<=32)

  // -------- prep --------
  hipMemsetAsync(TSb, 0, (size_t)kB * kD * sizeof(float), stream);
  transp_kernel<<<dim3(2, 16, 1), 256, 0, stream>>>(W_q, Wqt, 512, 64);
  transp_kernel<<<dim3(4, 16, 1), 256, 0, stream>>>(W_kv, Wkvt, 512, 128);
  transp_kernel<<<dim3(16, 2, 1), 256, 0, stream>>>(W_out, Wot, 64, 512);
  transp_kernel<<<dim3(2, 16, 1), 256, 0, stream>>>(ff_W1, Wf1t, 512, 64);
  transp_kernel<<<dim3(16, 2, 1), 256, 0, stream>>>(ff_W2, Wf2t, 64, 512);
  transp_kernel<<<dim3(16, 16, 6), 256, 0, stream>>>(g1_W, G1t, 512, 512);
  transp_kernel<<<dim3(16, 16, 6), 256, 0, stream>>>(g2_W, G2t, 512, 512);
  conv_bf16_kernel<<<(3072 * 512 / 8 + 255) / 256, 256, 0, stream>>>(
      memory, Memb, (size_t)3072 * 512);
  // ln1(aug) -> L1b bf16 and raw aug -> Xb bf16 (one fp32 read)
  ln1_dual_kernel<<<kTB / 4, 256, 0, stream>>>(aug, ln1_g, ln1_b, L1b, Xb, kTB);
  // kv = [memory; ln1] @ W_kv  (bf16 out)
  mfma_gemm_bt<128, 1><<<dim3(1, 3072 / 128), 256, 0, stream>>>(
      Memb, Wkvt, 512, np, KVb, 128);
  mfma_gemm_bt<128, 1><<<dim3(1, kTB / 128), 256, 0, stream>>>(
      L1b, Wkvt, 512, np, KVb + (size_t)3072 * 128, 128);
  // q = ln1 @ W_q (fp32 out)
  mfma_gemm_bt<64, 0><<<dim3(1, kTB / 128), 256, 0, stream>>>(
      L1b, Wqt, 512, np, Qb, 64);
  posp_kernel<<<kJ, 64, 0, stream>>>(W_p, Pb);
  attn_kernel<<<dim3(kB, kH), 128, 0, stream>>>(Qb, KVb, Pb, u, v, AVb);

  for (int c = 0; c < nch; ++c) {
    const int R0 = c * CR;
    const unsigned short* Xc = Xb + (size_t)R0 * kD;
    // y1 = av @ W_out (bf16 out)
    mfma_gemm_bt<128, 1><<<dim3(4, MG), 256, 0, stream>>>(
        AVb + (size_t)R0 * 64, Wot, 64, np, Ycb, 512);
    // gate1 (XCD-swizzled 1-D grids)
    mfma_gate_r<<<2 * MG, 512, 0, stream>>>(Ycb, Xc, G1t, g1_b, RXcb);
    mfma_gate_hz<false><<<4 * MG, 512, 0, stream>>>(
        Ycb, RXcb, Xc, G1t, g1_b, SRCcb, nullptr, R0);
    // ln2 (bf16 in/out)
    ln_b16_kernel<<<CR / 4, 256, 0, stream>>>(SRCcb, ln2_g, ln2_b, LN2cb, CR);
    // ff1 = relu(ln2 @ ff_W1 + b1) (bf16 out)
    mfma_gemm_bt<64, 2><<<dim3(1, MG), 256, 0, stream>>>(
        LN2cb, Wf1t, 512, ff_b1, F1cb, 64);
    // y2 = ff1 @ ff_W2 + b2 (bf16 out)
    mfma_gemm_bt<128, 3><<<dim3(4, MG), 256, 0, stream>>>(
        F1cb, Wf2t, 64, ff_b2, Ycb, 512);
    // gate2 + fused mean-pool
    mfma_gate_r<<<2 * MG, 512, 0, stream>>>(Ycb, SRCcb, G2t, g2_b, RXcb);
    mfma_gate_hz<true><<<4 * MG, 512, 0, stream>>>(
        Ycb, RXcb, SRCcb, G2t, g2_b, nullptr, TSb, R0);
  }

  // critic head (fp32)
  gemm_kernel<1, false><<<dim3(16, kB / 64), 256, 0, stream>>>(
      TSb, d1_W, 512, np, np, 0, d1_b, H1b, kB, 1024);
  gemm_kernel<1, true><<<dim3(8, kB / 64), 256, 0, stream>>>(
      H1b, d2_W, 1024, action, d2_W + (size_t)1024 * 512, 64, d2_b, H2b, kB, 512);
  gemm_kernel<1, false><<<dim3(5, kB / 64), 256, 0, stream>>>(
      H2b, d3_W, 512, np, np, 0, d3_b, H3b, kB, 300);
  gemm_kernel<1, false><<<dim3(1, kB / 64), 256, 0, stream>>>(
      H3b, d4_W, 300, np, np, 0, d4_b, out, kB, 1);
}

// Round 3
// 1427.708 us; speedup vs baseline: 1.1791x; 1.0859x over previous
//
#include <hip/hip_runtime.h>
#include <math.h>

namespace {

constexpr int kT = 128, kB = 512, kD = 512, kM = 6, kH = 2;
constexpr int kJ = kT + kM;          // 134
constexpr float kBG = 0.1f;
constexpr int kTB = kT * kB;         // 65536 rows
constexpr int kBK = 32;              // K-tile for MFMA kernels

typedef __attribute__((ext_vector_type(8))) short bf16x8;
typedef __attribute__((ext_vector_type(4))) float f32x4;
typedef __attribute__((ext_vector_type(8))) unsigned short us8;
typedef __attribute__((ext_vector_type(4))) unsigned short us4;

__device__ __forceinline__ float sigmoidf_(float x) {
  return 1.0f / (1.0f + __expf(-x));
}

__device__ __forceinline__ unsigned short bf16u(float f) {
  union { float f; unsigned u; } c; c.f = f;
  unsigned r = c.u + 0x7fffu + ((c.u >> 16) & 1u);
  return (unsigned short)(r >> 16);
}

__device__ __forceinline__ float b2f(unsigned short u) {
  union { unsigned u; float f; } c; c.u = (unsigned)u << 16;
  return c.f;
}

__device__ __forceinline__ void gl_lds16(const void* g, void* l) {
  __builtin_amdgcn_global_load_lds(
      (const __attribute__((address_space(1))) unsigned int*)g,
      (__attribute__((address_space(3))) unsigned int*)l, 16, 0, 0);
}

// counted vmcnt wait (T4): waits until <= N VMEM ops outstanding.
template <int N>
__device__ __forceinline__ void wvm_() {
  asm volatile("s_waitcnt vmcnt(%0)" :: "n"(N) : "memory");
}
__device__ __forceinline__ void bar_() { __builtin_amdgcn_s_barrier(); }
__device__ __forceinline__ void cfence_() { asm volatile("" ::: "memory"); }

// ---- transpose + cast: W fp32 [K][N] -> Wt bf16 [N][K]; dims mult of 32 ----
__global__ __launch_bounds__(256) void transp_kernel(const float* __restrict__ W,
                                                     unsigned short* __restrict__ Wt,
                                                     int K, int N) {
  __shared__ float t[32][33];
  const int n0 = blockIdx.x * 32, k0 = blockIdx.y * 32;
  const float* Wb = W + (size_t)blockIdx.z * K * N;
  unsigned short* Wtb = Wt + (size_t)blockIdx.z * K * N;
  int tx = threadIdx.x & 31, ty = threadIdx.x >> 5;  // 32 x 8
#pragma unroll
  for (int r = 0; r < 32; r += 8)
    t[ty + r][tx] = Wb[(size_t)(k0 + ty + r) * N + n0 + tx];
  __syncthreads();
#pragma unroll
  for (int r = 0; r < 32; r += 8)
    Wtb[(size_t)(n0 + ty + r) * K + k0 + tx] = bf16u(t[tx][ty + r]);
}

// ---- fp32 -> bf16 elementwise (n multiple of 8) ----
__global__ __launch_bounds__(256) void conv_bf16_kernel(const float* __restrict__ in,
                                                        unsigned short* __restrict__ outb,
                                                        size_t n) {
  size_t idx = ((size_t)blockIdx.x * 256 + threadIdx.x) * 8;
  if (idx >= n) return;
  float4 a = *(const float4*)(in + idx);
  float4 c = *(const float4*)(in + idx + 4);
  us8 o;
  o[0] = bf16u(a.x); o[1] = bf16u(a.y); o[2] = bf16u(a.z); o[3] = bf16u(a.w);
  o[4] = bf16u(c.x); o[5] = bf16u(c.y); o[6] = bf16u(c.z); o[7] = bf16u(c.w);
  *(us8*)(outb + idx) = o;
}

// ---- LN1 dual-output: LN(x) -> bf16 AND raw x -> bf16, one fp32 read ----
__global__ __launch_bounds__(256) void ln1_dual_kernel(const float* __restrict__ in,
                                                       const float* __restrict__ g,
                                                       const float* __restrict__ b,
                                                       unsigned short* __restrict__ outLN,
                                                       unsigned short* __restrict__ outRaw,
                                                       int nrows) {
  int wave = threadIdx.x >> 6, lane = threadIdx.x & 63;
  int row = blockIdx.x * 4 + wave;
  if (row >= nrows) return;
  const float* p = in + (size_t)row * kD + lane * 8;
  float4 a = *(const float4*)p;
  float4 c = *(const float4*)(p + 4);
  float v[8] = {a.x, a.y, a.z, a.w, c.x, c.y, c.z, c.w};
  float s = 0.f;
#pragma unroll
  for (int i = 0; i < 8; ++i) s += v[i];
#pragma unroll
  for (int off = 32; off; off >>= 1) s += __shfl_xor(s, off);
  float mu = s * (1.0f / 512.0f);
  float q = 0.f;
#pragma unroll
  for (int i = 0; i < 8; ++i) { float d = v[i] - mu; q += d * d; }
#pragma unroll
  for (int off = 32; off; off >>= 1) q += __shfl_xor(q, off);
  float rstd = rsqrtf(q * (1.0f / 512.0f) + 1e-5f);
  us8 oln, oraw;
#pragma unroll
  for (int i = 0; i < 8; ++i) {
    int col = lane * 8 + i;
    oln[i] = bf16u((v[i] - mu) * rstd * g[col] + b[col]);
    oraw[i] = bf16u(v[i]);
  }
  size_t off8 = (size_t)row * kD + lane * 8;
  *(us8*)(outLN + off8) = oln;
  *(us8*)(outRaw + off8) = oraw;
}

// ---- LN with bf16 input -> bf16 out ----
__global__ __launch_bounds__(256) void ln_b16_kernel(const unsigned short* __restrict__ in,
                                                     const float* __restrict__ g,
                                                     const float* __restrict__ b,
                                                     unsigned short* __restrict__ outb,
                                                     int nrows) {
  int wave = threadIdx.x >> 6, lane = threadIdx.x & 63;
  int row = blockIdx.x * 4 + wave;
  if (row >= nrows) return;
  us8 iv = *(const us8*)(in + (size_t)row * kD + lane * 8);
  float v[8];
#pragma unroll
  for (int i = 0; i < 8; ++i) v[i] = b2f(iv[i]);
  float s = 0.f;
#pragma unroll
  for (int i = 0; i < 8; ++i) s += v[i];
#pragma unroll
  for (int off = 32; off; off >>= 1) s += __shfl_xor(s, off);
  float mu = s * (1.0f / 512.0f);
  float q = 0.f;
#pragma unroll
  for (int i = 0; i < 8; ++i) { float d = v[i] - mu; q += d * d; }
#pragma unroll
  for (int off = 32; off; off >>= 1) q += __shfl_xor(q, off);
  float rstd = rsqrtf(q * (1.0f / 512.0f) + 1e-5f);
  us8 o;
#pragma unroll
  for (int i = 0; i < 8; ++i) {
    int col = lane * 8 + i;
    o[i] = bf16u((v[i] - mu) * rstd * g[col] + b[col]);
  }
  *(us8*)(outb + (size_t)row * kD + lane * 8) = o;
}

// ============ MFMA GEMM, B^T input: C[M][N] = A[M][K] @ Bt[N][K]^T ==========
// 128 x TN tile, 256 threads (4 waves), BK=32, global_load_lds width 16.
// Depth-3 LDS ring + counted vmcnt (T4): stage(t+2), wait vmcnt(2*NLD) so
// only stage(t) must have landed; raw barriers; never drain in main loop.
// EPI: 0 = fp32 out, 1 = bf16 out, 2 = bias+relu+bf16, 3 = bias+bf16.
template <int TN, int EPI>
__global__ __launch_bounds__(256) void mfma_gemm_bt(
    const unsigned short* __restrict__ A, const unsigned short* __restrict__ Bt,
    int K, const float* __restrict__ bias, void* __restrict__ Cv, int N) {
  constexpr int MI = (TN == 128) ? 4 : 2;
  constexpr int NJ = 4;
  constexpr int BCH = TN * 64 / 1024;      // B chunks (8 or 4)
  constexpr int NLD = 2 + BCH / 4;         // per-wave gl_lds ops per stage
  __shared__ __align__(16) unsigned short As[3][128 * kBK];
  __shared__ __align__(16) unsigned short Bs[3][TN * kBK];
  const int tid = threadIdx.x;
  const int lane = tid & 63, wv = tid >> 6;
  const int ml = lane & 15, qd = lane >> 4;
  const int m0 = blockIdx.y * 128, n0 = blockIdx.x * TN;
  const int mw0 = (TN == 128) ? (wv >> 1) * 64 : wv * 32;
  const int nw0 = (TN == 128) ? (wv & 1) * 64 : 0;
  const size_t ldA = (size_t)K * 2, ldB = (size_t)K * 2;
  const char* Ab = (const char*)A + (size_t)m0 * ldA;
  const char* Bb = (const char*)Bt + (size_t)n0 * ldB;
  auto stg = [&](int k0, int buf) {
#pragma unroll
    for (int c = wv; c < 8; c += 4) {
      int fb = c * 1024 + lane * 16;
      gl_lds16(Ab + (size_t)(fb >> 6) * ldA + (fb & 63) + (size_t)k0 * 2,
               (char*)As[buf] + c * 1024);
    }
#pragma unroll
    for (int c = wv; c < BCH; c += 4) {
      int fb = c * 1024 + lane * 16;
      gl_lds16(Bb + (size_t)(fb >> 6) * ldB + (fb & 63) + (size_t)k0 * 2,
               (char*)Bs[buf] + c * 1024);
    }
  };
  f32x4 acc[MI][NJ];
#pragma unroll
  for (int i = 0; i < MI; ++i)
#pragma unroll
    for (int j = 0; j < NJ; ++j) acc[i][j] = (f32x4)0.f;
  stg(0, 0);
  stg(kBK, 1);                    // K >= 64 at all call sites
  int cb = 0;
  for (int k0 = 0; k0 < K; k0 += kBK) {
    const int sb = (cb == 0) ? 2 : cb - 1;
    if (k0 + 2 * kBK < K) { stg(k0 + 2 * kBK, sb); wvm_<2 * NLD>(); }
    else if (k0 + kBK < K) { wvm_<NLD>(); }
    else { wvm_<0>(); }
    bar_(); cfence_();
    bf16x8 af[MI], bfr[NJ];
#pragma unroll
    for (int i = 0; i < MI; ++i)
      af[i] = *(const bf16x8*)(As[cb] + (mw0 + i * 16 + ml) * kBK + qd * 8);
#pragma unroll
    for (int j = 0; j < NJ; ++j)
      bfr[j] = *(const bf16x8*)(Bs[cb] + (nw0 + j * 16 + ml) * kBK + qd * 8);
#pragma unroll
    for (int i = 0; i < MI; ++i)
#pragma unroll
      for (int j = 0; j < NJ; ++j)
        acc[i][j] = __builtin_amdgcn_mfma_f32_16x16x32_bf16(af[i], bfr[j], acc[i][j], 0, 0, 0);
    cfence_(); bar_();
    cb = (cb == 2) ? 0 : cb + 1;
  }
#pragma unroll
  for (int i = 0; i < MI; ++i)
#pragma unroll
    for (int j = 0; j < NJ; ++j)
#pragma unroll
      for (int r = 0; r < 4; ++r) {
        int m = m0 + mw0 + i * 16 + qd * 4 + r;
        int n = n0 + nw0 + j * 16 + ml;
        float val = acc[i][j][r];
        if (EPI >= 2) val += bias[n];
        if (EPI == 2) val = fmaxf(val, 0.f);
        size_t idx = (size_t)m * N + n;
        if (EPI == 0) ((float*)Cv)[idx] = val;
        else ((unsigned short*)Cv)[idx] = bf16u(val);
      }
}

// XCD swizzle: 1-D grid of MG*NB blocks. All NB n-blocks of one m-group land
// on the SAME XCD in ADJACENT dispatch slots -> A tile fetched once into that
// XCD's L2 and shared (perf-only heuristic; correctness never depends on it).
template <int NBLOG>
__device__ __forceinline__ void xcd_decode(int& m0, int& n0, int tileN) {
  const int L = blockIdx.x;
  const int xcd = L & 7;
  const int s = L >> 3;
  const int mgPerX = (int)(gridDim.x >> (3 + NBLOG));
  const int mg = xcd * mgPerX + (s >> NBLOG);
  const int nb = s & ((1 << NBLOG) - 1);
  m0 = mg * 128;
  n0 = nb * tileN;
}

// ====== gate r: 128x256 tile, 512 threads (8 waves, 2M x 4N), per-wave 64x64.
// Depth-3 ring + counted vmcnt; 2 passes flattened with cross-pass prefetch.
// acc = Y@W0t^T + X@W1t^T ; RX = bf16(sigmoid(acc+b0+b1)*x). LDS 72 KB.
__global__ __launch_bounds__(512, 4) void mfma_gate_r(
    const unsigned short* __restrict__ Yb, const unsigned short* __restrict__ Xb,
    const unsigned short* __restrict__ Wt, const float* __restrict__ gb,
    unsigned short* __restrict__ RX) {
  __shared__ __align__(16) unsigned short As[3][128 * kBK];   // 24 KB
  __shared__ __align__(16) unsigned short Bs[3][256 * kBK];   // 48 KB
  const int tid = threadIdx.x;
  const int lane = tid & 63, wv = tid >> 6;  // 8 waves
  const int ml = lane & 15, qd = lane >> 4;
  int m0, n0;
  xcd_decode<1>(m0, n0, 256);
  const int mw0 = (wv & 1) * 64, nw0 = (wv >> 1) * 64;
  const size_t ld = (size_t)kD * 2;
  const size_t DD = (size_t)kD * kD;
  const char* Abp[2], *Bbp[2];
  {
    const unsigned short* Ap[2] = {Yb, Xb};
#pragma unroll
    for (int p = 0; p < 2; ++p) {
      Abp[p] = (const char*)Ap[p] + (size_t)m0 * ld;
      Bbp[p] = (const char*)(Wt + (size_t)p * DD) + (size_t)n0 * ld;
    }
  }
  auto stg = [&](const char* Ab, const char* Bb, int k0, int buf) {
    {
      int fb = wv * 1024 + lane * 16;
      gl_lds16(Ab + (size_t)(fb >> 6) * ld + (fb & 63) + (size_t)k0 * 2,
               (char*)As[buf] + wv * 1024);
    }
#pragma unroll
    for (int c = wv; c < 16; c += 8) {
      int fb = c * 1024 + lane * 16;
      gl_lds16(Bb + (size_t)(fb >> 6) * ld + (fb & 63) + (size_t)k0 * 2,
               (char*)Bs[buf] + c * 1024);
    }
  };  // NLD = 3 per wave
  f32x4 acc[4][4];
#pragma unroll
  for (int i = 0; i < 4; ++i)
#pragma unroll
    for (int j = 0; j < 4; ++j) acc[i][j] = (f32x4)0.f;
  stg(Abp[0], Bbp[0], 0, 0);
  stg(Abp[0], Bbp[0], kBK, 1);
  int cb = 0;
#pragma unroll
  for (int p = 0; p < 2; ++p) {
    for (int k = 0; k < 16; ++k) {
      const int sb = (cb == 0) ? 2 : cb - 1;
      if (k < 14) { stg(Abp[p], Bbp[p], (k + 2) * kBK, sb); wvm_<6>(); }
      else if (p < 1) { stg(Abp[p + 1], Bbp[p + 1], (k - 14) * kBK, sb); wvm_<6>(); }
      else if (k == 14) { wvm_<3>(); }
      else { wvm_<0>(); }
      bar_(); cfence_();
      bf16x8 af[4], bfr[4];
#pragma unroll
      for (int i = 0; i < 4; ++i)
        af[i] = *(const bf16x8*)(As[cb] + (mw0 + i * 16 + ml) * kBK + qd * 8);
#pragma unroll
      for (int j = 0; j < 4; ++j)
        bfr[j] = *(const bf16x8*)(Bs[cb] + (nw0 + j * 16 + ml) * kBK + qd * 8);
#pragma unroll
      for (int i = 0; i < 4; ++i)
#pragma unroll
        for (int j = 0; j < 4; ++j)
          acc[i][j] = __builtin_amdgcn_mfma_f32_16x16x32_bf16(af[i], bfr[j], acc[i][j], 0, 0, 0);
      cfence_(); bar_();
      cb = (cb == 2) ? 0 : cb + 1;
    }
  }
#pragma unroll
  for (int i = 0; i < 4; ++i)
#pragma unroll
    for (int j = 0; j < 4; ++j)
#pragma unroll
      for (int r = 0; r < 4; ++r) {
        int m = m0 + mw0 + i * 16 + qd * 4 + r;
        int n = n0 + nw0 + j * 16 + ml;
        float rg = sigmoidf_(acc[i][j][r] + gb[n] + gb[kD + n]);
        size_t idx = (size_t)m * kD + n;
        RX[idx] = bf16u(rg * b2f(Xb[idx]));
      }
}

// ====== gate h+z: 128x128 tile, 512 threads (8 waves, 4M x 2N), per-wave
// 32x64; depth-3 ring + counted vmcnt; 4 passes flattened, cross-pass
// prefetch. accH = Y@W4 + RX@W5 ; accZ = Y@W2 + X@W3. LDS 48 KB.
// out = (1-z)*x + z*tanh(accH+b4+b5), z = sigmoid(accZ+b2+b3-BG).
// POOL=false: OUTb bf16. POOL=true: atomic mean-pool into TS.
template <bool POOL>
__global__ __launch_bounds__(512, 4) void mfma_gate_hz(
    const unsigned short* __restrict__ Yb, const unsigned short* __restrict__ RXb,
    const unsigned short* __restrict__ Xb, const unsigned short* __restrict__ Wt,
    const float* __restrict__ gb, unsigned short* __restrict__ OUTb,
    float* __restrict__ TS, int rowoff) {
  __shared__ __align__(16) unsigned short As[3][128 * kBK];  // 24 KB
  __shared__ __align__(16) unsigned short Bs[3][128 * kBK];  // 24 KB
  const int tid = threadIdx.x;
  const int lane = tid & 63, wv = tid >> 6;  // 8 waves
  const int ml = lane & 15, qd = lane >> 4;
  int m0, n0;
  xcd_decode<2>(m0, n0, 128);
  const int mw0 = (wv & 3) * 32, nw0 = (wv >> 2) * 64;
  const size_t ld = (size_t)kD * 2;
  const size_t DD = (size_t)kD * kD;
  f32x4 accH[2][4], accZ[2][4];
#pragma unroll
  for (int i = 0; i < 2; ++i)
#pragma unroll
    for (int j = 0; j < 4; ++j) { accH[i][j] = (f32x4)0.f; accZ[i][j] = (f32x4)0.f; }
  const char* Abp[4], *Bbp[4];
  {
    const unsigned short* Ap[4] = {Yb, RXb, Yb, Xb};
    const int wsel[4] = {4, 5, 2, 3};
#pragma unroll
    for (int p = 0; p < 4; ++p) {
      Abp[p] = (const char*)Ap[p] + (size_t)m0 * ld;
      Bbp[p] = (const char*)(Wt + (size_t)wsel[p] * DD) + (size_t)n0 * ld;
    }
  }
  auto stg = [&](const char* Ab, const char* Bb, int k0, int buf) {
    int fb = wv * 1024 + lane * 16;
    size_t go = (size_t)(fb >> 6) * ld + (fb & 63) + (size_t)k0 * 2;
    gl_lds16(Ab + go, (char*)As[buf] + wv * 1024);
    gl_lds16(Bb + go, (char*)Bs[buf] + wv * 1024);
  };  // NLD = 2 per wave
  stg(Abp[0], Bbp[0], 0, 0);
  stg(Abp[0], Bbp[0], kBK, 1);
  int cb = 0;
#pragma unroll
  for (int p = 0; p < 4; ++p) {
    f32x4 (*acc)[4] = (p < 2) ? accH : accZ;
    for (int k = 0; k < 16; ++k) {
      const int sb = (cb == 0) ? 2 : cb - 1;
      if (k < 14) { stg(Abp[p], Bbp[p], (k + 2) * kBK, sb); wvm_<4>(); }
      else if (p < 3) { stg(Abp[p + 1], Bbp[p + 1], (k - 14) * kBK, sb); wvm_<4>(); }
      else if (k == 14) { wvm_<2>(); }
      else { wvm_<0>(); }
      bar_(); cfence_();
      bf16x8 af[2], bfr[4];
#pragma unroll
      for (int i = 0; i < 2; ++i)
        af[i] = *(const bf16x8*)(As[cb] + (mw0 + i * 16 + ml) * kBK + qd * 8);
#pragma unroll
      for (int j = 0; j < 4; ++j)
        bfr[j] = *(const bf16x8*)(Bs[cb] + (nw0 + j * 16 + ml) * kBK + qd * 8);
#pragma unroll
      for (int i = 0; i < 2; ++i)
#pragma unroll
        for (int j = 0; j < 4; ++j)
          acc[i][j] = __builtin_amdgcn_mfma_f32_16x16x32_bf16(af[i], bfr[j], acc[i][j], 0, 0, 0);
      cfence_(); bar_();
      cb = (cb == 2) ? 0 : cb + 1;
    }
  }
#pragma unroll
  for (int i = 0; i < 2; ++i)
#pragma unroll
    for (int j = 0; j < 4; ++j)
#pragma unroll
      for (int r = 0; r < 4; ++r) {
        int m = m0 + mw0 + i * 16 + qd * 4 + r;
        int n = n0 + nw0 + j * 16 + ml;
        float z = sigmoidf_(accZ[i][j][r] + gb[2 * kD + n] + gb[3 * kD + n] - kBG);
        float hc = tanhf(accH[i][j][r] + gb[4 * kD + n] + gb[5 * kD + n]);
        size_t idx = (size_t)m * kD + n;
        float val = (1.0f - z) * b2f(Xb[idx]) + z * hc;
        if (POOL) {
          int b = (rowoff + m) & (kB - 1);
          atomicAdd(TS + (size_t)b * kD + n, val * (1.0f / kT));
        } else {
          OUTb[idx] = bf16u(val);
        }
      }
}

// -------- Positional embedding projection ----------
__global__ __launch_bounds__(64) void posp_kernel(const float* __restrict__ Wp,
                                                  float* __restrict__ P) {
  __shared__ float emb[512];
  int jj = blockIdx.x;
  int t = threadIdx.x;
  float pos = (float)(kJ - 1 - jj);
#pragma unroll
  for (int r = 0; r < 8; ++r) {
    int d = t + r * 64;
    int i = (d < 256) ? d : d - 256;
    float invf = expf(-((float)(2 * i) * (1.0f / 512.0f)) * 9.210340371976184f);
    float si = pos * invf;
    emb[d] = (d < 256) ? sinf(si) : cosf(si);
  }
  __syncthreads();
  float acc = 0.f;
  for (int d = 0; d < 512; ++d) acc = fmaf(emb[d], Wp[d * 64 + t], acc);
  P[jj * 64 + t] = acc;
}

// -------- Attention (fp32 math), KV bf16 in, AV out as bf16 ----------
__global__ __launch_bounds__(128) void attn_kernel(
    const float* __restrict__ Q, const unsigned short* __restrict__ KV,
    const float* __restrict__ P, const float* __restrict__ U,
    const float* __restrict__ V, unsigned short* __restrict__ AV) {
  __shared__ float ks[kJ][32];
  __shared__ float vs[kJ][32];
  __shared__ float ps[32][kJ + 2];
  const int b = blockIdx.x, h = blockIdx.y;
  const int tid = threadIdx.x;
  for (int idx = tid; idx < kJ * 8; idx += 128) {
    int j = idx >> 3, seg = idx & 7;
    const unsigned short* src = KV + ((size_t)(j * kB + b)) * 128 + h * 32 + seg * 4;
    us4 kq = *(const us4*)src;
    us4 vq = *(const us4*)(src + 64);
#pragma unroll
    for (int e = 0; e < 4; ++e) {
      ks[j][seg * 4 + e] = b2f(kq[e]);
      vs[j][seg * 4 + e] = b2f(vq[e]);
    }
  }
  for (int idx = tid; idx < kJ * 8; idx += 128) {
    int j = idx >> 3, seg = idx & 7;
    float4 pq = *(const float4*)(P + j * 64 + h * 32 + seg * 4);
    ps[seg * 4 + 0][j] = pq.x;
    ps[seg * 4 + 1][j] = pq.y;
    ps[seg * 4 + 2][j] = pq.z;
    ps[seg * 4 + 3][j] = pq.w;
  }
  __syncthreads();
  const int i = tid;
  float qu[32], qv[32];
  const float* qp = Q + ((size_t)(i * kB + b)) * 64 + h * 32;
#pragma unroll
  for (int d = 0; d < 32; ++d) {
    float qd = qp[d];
    qu[d] = qd + U[h * 32 + d];
    qv[d] = qd + V[h * 32 + d];
  }
  float m = -INFINITY, l = 0.f, acc[32] = {};
  const float scale = 0.17677669529663687f;
  for (int j = 0; j <= i + kM; ++j) {
    float s = 0.f;
#pragma unroll
    for (int d = 0; d < 32; d += 4) {
      float4 k4 = *(const float4*)&ks[j][d];
      s = fmaf(qu[d + 0], k4.x, s);
      s = fmaf(qu[d + 1], k4.y, s);
      s = fmaf(qu[d + 2], k4.z, s);
      s = fmaf(qu[d + 3], k4.w, s);
    }
    int jj = j + (kT - 1) - i;
#pragma unroll
    for (int d = 0; d < 32; ++d) s = fmaf(qv[d], ps[d][jj], s);
    float ls = s * scale;
    float nm = fmaxf(m, ls);
    float w = __expf(ls - nm);
    float f = __expf(m - nm);
    l = l * f + w;
#pragma unroll
    for (int d = 0; d < 32; d += 4) {
      float4 v4 = *(const float4*)&vs[j][d];
      acc[d + 0] = fmaf(acc[d + 0], f, w * v4.x);
      acc[d + 1] = fmaf(acc[d + 1], f, w * v4.y);
      acc[d + 2] = fmaf(acc[d + 2], f, w * v4.z);
      acc[d + 3] = fmaf(acc[d + 3], f, w * v4.w);
    }
    m = nm;
  }
  float inv = 1.0f / l;
  unsigned short* o = AV + ((size_t)(i * kB + b)) * 64 + h * 32;
#pragma unroll
  for (int d = 0; d < 32; ++d) o[d] = bf16u(acc[d] * inv);
}

// -------- fp32 fallback GEMM for the small critic head --------
template <int ACTF, bool DUAL>
__global__ __launch_bounds__(256) void gemm_kernel(
    const float* __restrict__ A1, const float* __restrict__ Bm1, int K1,
    const float* __restrict__ A2, const float* __restrict__ Bm2, int K2,
    const float* __restrict__ bias, float* __restrict__ C, int Mrows, int N) {
  __shared__ float As[16][68];
  __shared__ float Bs[16][68];
  const int tid = threadIdx.x;
  const int tx = tid & 15, ty = tid >> 4;
  const int m0 = blockIdx.y * 64, n0 = blockIdx.x * 64;
  const int ar = tid >> 2, aseg = tid & 3;
  float acc[4][4] = {};
#pragma unroll
  for (int pass = 0; pass < (DUAL ? 2 : 1); ++pass) {
    const float* A = (DUAL && pass) ? A2 : A1;
    const float* Bm = (DUAL && pass) ? Bm2 : Bm1;
    const int K = (DUAL && pass) ? K2 : K1;
    for (int k0 = 0; k0 < K; k0 += 16) {
      {
        int row = m0 + ar;
        int kb = k0 + aseg * 4;
        float x0 = 0.f, x1 = 0.f, x2 = 0.f, x3 = 0.f;
        if (row < Mrows) {
          const float* ap = A + (size_t)row * K + kb;
          if (kb + 3 < K) {
            float4 t = *(const float4*)ap;
            x0 = t.x; x1 = t.y; x2 = t.z; x3 = t.w;
          } else {
            if (kb + 0 < K) x0 = ap[0];
            if (kb + 1 < K) x1 = ap[1];
            if (kb + 2 < K) x2 = ap[2];
          }
        }
        As[aseg * 4 + 0][ar] = x0;
        As[aseg * 4 + 1][ar] = x1;
        As[aseg * 4 + 2][ar] = x2;
        As[aseg * 4 + 3][ar] = x3;
      }
      {
        int krow = k0 + ty;
        int nb = n0 + tx * 4;
        float y0 = 0.f, y1 = 0.f, y2 = 0.f, y3 = 0.f;
        if (krow < K) {
          const float* bp = Bm + (size_t)krow * N + nb;
          if (nb + 3 < N) {
            float4 t = *(const float4*)bp;
            y0 = t.x; y1 = t.y; y2 = t.z; y3 = t.w;
          } else {
            if (nb + 0 < N) y0 = bp[0];
            if (nb + 1 < N) y1 = bp[1];
            if (nb + 2 < N) y2 = bp[2];
          }
        }
        *(float4*)&Bs[ty][tx * 4] = make_float4(y0, y1, y2, y3);
      }
      __syncthreads();
#pragma unroll
      for (int kk = 0; kk < 16; ++kk) {
        float a[4], bb[4];
        *(float4*)a = *(const float4*)&As[kk][ty * 4];
        *(float4*)bb = *(const float4*)&Bs[kk][tx * 4];
#pragma unroll
        for (int i = 0; i < 4; ++i)
#pragma unroll
          for (int j = 0; j < 4; ++j) acc[i][j] = fmaf(a[i], bb[j], acc[i][j]);
      }
      __syncthreads();
    }
  }
#pragma unroll
  for (int i = 0; i < 4; ++i) {
    int m = m0 + ty * 4 + i;
    if (m >= Mrows) continue;
#pragma unroll
    for (int j = 0; j < 4; ++j) {
      int n = n0 + tx * 4 + j;
      if (n >= N) continue;
      float val = acc[i][j];
      if (bias) val += bias[n];
      if (ACTF == 1) val = fmaxf(val, 0.f);
      C[(size_t)m * N + n] = val;
    }
  }
}

}  // namespace

extern "C" void kernel_launch(void* const* d_in, const int* in_sizes, int n_in,
                              void* d_out, int out_size, void* d_ws, size_t ws_size,
                              hipStream_t stream) {
  (void)in_sizes; (void)n_in; (void)out_size;
  const float* aug    = (const float*)d_in[0];
  const float* action = (const float*)d_in[1];
  const float* memory = (const float*)d_in[2];
  const float* W_q    = (const float*)d_in[3];
  const float* W_kv   = (const float*)d_in[4];
  const float* W_p    = (const float*)d_in[5];
  const float* W_out  = (const float*)d_in[6];
  const float* u      = (const float*)d_in[7];
  const float* v      = (const float*)d_in[8];
  const float* ln1_g  = (const float*)d_in[9];
  const float* ln1_b  = (const float*)d_in[10];
  const float* ln2_g  = (const float*)d_in[11];
  const float* ln2_b  = (const float*)d_in[12];
  const float* ff_W1  = (const float*)d_in[13];
  const float* ff_b1  = (const float*)d_in[14];
  const float* ff_W2  = (const float*)d_in[15];
  const float* ff_b2  = (const float*)d_in[16];
  const float* g1_W   = (const float*)d_in[17];
  const float* g1_b   = (const float*)d_in[18];
  const float* g2_W   = (const float*)d_in[19];
  const float* g2_b   = (const float*)d_in[20];
  const float* d1_W   = (const float*)d_in[21];
  const float* d1_b   = (const float*)d_in[22];
  const float* d2_W   = (const float*)d_in[23];
  const float* d2_b   = (const float*)d_in[24];
  const float* d3_W   = (const float*)d_in[25];
  const float* d3_b   = (const float*)d_in[26];
  const float* d4_W   = (const float*)d_in[27];
  const float* d4_b   = (const float*)d_in[28];
  float* out = (float*)d_out;

  // ---------------- workspace carve ----------------
  char* base = (char*)d_ws;
  auto alloc = [&](size_t bytes) -> char* {
    char* p = base;
    base += (bytes + 255) & ~(size_t)255;
    return p;
  };
  unsigned short* Wqt  = (unsigned short*)alloc((size_t)64 * 512 * 2);
  unsigned short* Wkvt = (unsigned short*)alloc((size_t)128 * 512 * 2);
  unsigned short* Wot  = (unsigned short*)alloc((size_t)512 * 64 * 2);
  unsigned short* Wf1t = (unsigned short*)alloc((size_t)64 * 512 * 2);
  unsigned short* Wf2t = (unsigned short*)alloc((size_t)512 * 64 * 2);
  unsigned short* G1t  = (unsigned short*)alloc((size_t)6 * 512 * 512 * 2);
  unsigned short* G2t  = (unsigned short*)alloc((size_t)6 * 512 * 512 * 2);
  unsigned short* Memb = (unsigned short*)alloc((size_t)3072 * 512 * 2);
  unsigned short* KVb  = (unsigned short*)alloc((size_t)kJ * kB * 128 * 2);
  float* Qb  = (float*)alloc((size_t)kTB * 64 * 4);
  unsigned short* AVb = (unsigned short*)alloc((size_t)kTB * 64 * 2);
  unsigned short* Xb  = (unsigned short*)alloc((size_t)kTB * kD * 2);  // raw aug bf16
  float* Pb  = (float*)alloc((size_t)kJ * 64 * 4);
  float* TSb = (float*)alloc((size_t)kB * kD * 4);
  float* H1b = (float*)alloc((size_t)kB * 1024 * 4);
  float* H2b = (float*)alloc((size_t)kB * 512 * 4);
  float* H3b = (float*)alloc((size_t)kB * 320 * 4);
  size_t fixedBytes = (size_t)(base - (char*)d_ws);
  const size_t ln1Bytes = (size_t)kTB * kD * 2;  // L1b overlaps chunk region
  int nch = 1;
  while (nch < 32) {
    size_t chunkBytes = (size_t)(kTB / nch) * 4224 + 4096;
    size_t reuse = chunkBytes > ln1Bytes ? chunkBytes : ln1Bytes;
    if (fixedBytes + reuse <= ws_size) break;
    nch <<= 1;
  }
  const int CR = kTB / nch;
  char* R = base;
  unsigned short* L1b = (unsigned short*)R;  // ln1(aug) bf16 (dead before chunks)
  char* rp = R;
  auto ralloc = [&](size_t bytes) -> char* {
    char* p = rp;
    rp += (bytes + 255) & ~(size_t)255;
    return p;
  };
  unsigned short* Ycb   = (unsigned short*)ralloc((size_t)CR * 512 * 2);
  unsigned short* RXcb  = (unsigned short*)ralloc((size_t)CR * 512 * 2);
  unsigned short* SRCcb = (unsigned short*)ralloc((size_t)CR * 512 * 2);
  unsigned short* LN2cb = (unsigned short*)ralloc((size_t)CR * 512 * 2);
  unsigned short* F1cb  = (unsigned short*)ralloc((size_t)CR * 64 * 2);

  const float* np = nullptr;
  const int MG = CR / 128;  // m-groups per chunk (divisible by 8 for nch<=32)

  // -------- prep --------
  hipMemsetAsync(TSb, 0, (size_t)kB * kD * sizeof(float), stream);
  transp_kernel<<<dim3(2, 16, 1), 256, 0, stream>>>(W_q, Wqt, 512, 64);
  transp_kernel<<<dim3(4, 16, 1), 256, 0, stream>>>(W_kv, Wkvt, 512, 128);
  transp_kernel<<<dim3(16, 2, 1), 256, 0, stream>>>(W_out, Wot, 64, 512);
  transp_kernel<<<dim3(2, 16, 1), 256, 0, stream>>>(ff_W1, Wf1t, 512, 64);
  transp_kernel<<<dim3(16, 2, 1), 256, 0, stream>>>(ff_W2, Wf2t, 64, 512);
  transp_kernel<<<dim3(16, 16, 6), 256, 0, stream>>>(g1_W, G1t, 512, 512);
  transp_kernel<<<dim3(16, 16, 6), 256, 0, stream>>>(g2_W, G2t, 512, 512);
  conv_bf16_kernel<<<(3072 * 512 / 8 + 255) / 256, 256, 0, stream>>>(
      memory, Memb, (size_t)3072 * 512);
  // ln1(aug) -> L1b bf16 and raw aug -> Xb bf16 (one fp32 read)
  ln1_dual_kernel<<<kTB / 4, 256, 0, stream>>>(aug, ln1_g, ln1_b, L1b, Xb, kTB);
  // kv = [memory; ln1] @ W_kv  (bf16 out)
  mfma_gemm_bt<128, 1><<<dim3(1, 3072 / 128), 256, 0, stream>>>(
      Memb, Wkvt, 512, np, KVb, 128);
  mfma_gemm_bt<128, 1><<<dim3(1, kTB / 128), 256, 0, stream>>>(
      L1b, Wkvt, 512, np, KVb + (size_t)3072 * 128, 128);
  // q = ln1 @ W_q (fp32 out)
  mfma_gemm_bt<64, 0><<<dim3(1, kTB / 128), 256, 0, stream>>>(
      L1b, Wqt, 512, np, Qb, 64);
  posp_kernel<<<kJ, 64, 0, stream>>>(W_p, Pb);
  attn_kernel<<<dim3(kB, kH), 128, 0, stream>>>(Qb, KVb, Pb, u, v, AVb);

  for (int c = 0; c < nch; ++c) {
    const int R0 = c * CR;
    const unsigned short* Xc = Xb + (size_t)R0 * kD;
    // y1 = av @ W_out (bf16 out)
    mfma_gemm_bt<128, 1><<<dim3(4, MG), 256, 0, stream>>>(
        AVb + (size_t)R0 * 64, Wot, 64, np, Ycb, 512);
    // gate1 (XCD-swizzled 1-D grids)
    mfma_gate_r<<<2 * MG, 512, 0, stream>>>(Ycb, Xc, G1t, g1_b, RXcb);
    mfma_gate_hz<false><<<4 * MG, 512, 0, stream>>>(
        Ycb, RXcb, Xc, G1t, g1_b, SRCcb, nullptr, R0);
    // ln2 (bf16 in/out)
    ln_b16_kernel<<<CR / 4, 256, 0, stream>>>(SRCcb, ln2_g, ln2_b, LN2cb, CR);
    // ff1 = relu(ln2 @ ff_W1 + b1) (bf16 out)
    mfma_gemm_bt<64, 2><<<dim3(1, MG), 256, 0, stream>>>(
        LN2cb, Wf1t, 512, ff_b1, F1cb, 64);
    // y2 = ff1 @ ff_W2 + b2 (bf16 out)
    mfma_gemm_bt<128, 3><<<dim3(4, MG), 256, 0, stream>>>(
        F1cb, Wf2t, 64, ff_b2, Ycb, 512);
    // gate2 + fused mean-pool
    mfma_gate_r<<<2 * MG, 512, 0, stream>>>(Ycb, SRCcb, G2t, g2_b, RXcb);
    mfma_gate_hz<true><<<4 * MG, 512, 0, stream>>>(
        Ycb, RXcb, SRCcb, G2t, g2_b, nullptr, TSb, R0);
  }

  // critic head (fp32)
  gemm_kernel<1, false><<<dim3(16, kB / 64), 256, 0, stream>>>(
      TSb, d1_W, 512, np, np, 0, d1_b, H1b, kB, 1024);
  gemm_kernel<1, true><<<dim3(8, kB / 64), 256, 0, stream>>>(
      H1b, d2_W, 1024, action, d2_W + (size_t)1024 * 512, 64, d2_b, H2b, kB, 512);
  gemm_kernel<1, false><<<dim3(5, kB / 64), 256, 0, stream>>>(
      H2b, d3_W, 512, np, np, 0, d3_b, H3b, kB, 300);
  gemm_kernel<1, false><<<dim3(1, kB / 64), 256, 0, stream>>>(
      H3b, d4_W, 300, np, np, 0, d4_b, out, kB, 1);
}